// Round 1
// baseline (341.939 us; speedup 1.0000x reference)
//
#include <hip/hip_runtime.h>

#define D_MODEL 768
#define D_INNER 1536
#define D_STATE 16
#define DT_RANK 96
#define BB 2
#define LL 2048
#define TT (BB*LL)          // 4096 tokens
#define NC 64               // chunks per sequence
#define CL 32               // chunk length
#define SKK 4               // split-K factor for xdbl GEMM
#define LOG2E 1.44269504f

typedef unsigned short u16;
typedef short bf16x8 __attribute__((ext_vector_type(8)));
typedef unsigned short u16x8 __attribute__((ext_vector_type(8)));
typedef float f32x4  __attribute__((ext_vector_type(4)));

__device__ __forceinline__ float bf2f(u16 u) {
    union { unsigned int i; float f; } c; c.i = ((unsigned int)u) << 16; return c.f;
}
__device__ __forceinline__ u16 f2bf(float f) {
    union { float f; unsigned int i; } c; c.f = f;
    unsigned int x = c.i;
    return (u16)((x + 0x7fffu + ((x >> 16) & 1u)) >> 16);   // RNE
}
__device__ __forceinline__ float bfu_lo(unsigned int u) {
    union { unsigned int i; float f; } c; c.i = u << 16; return c.f;
}
__device__ __forceinline__ float bfu_hi(unsigned int u) {
    union { unsigned int i; float f; } c; c.i = u & 0xFFFF0000u; return c.f;
}
__device__ __forceinline__ float ldx(const void* p, size_t i, bool f32) {
    return f32 ? ((const float*)p)[i] : bf2f(((const u16*)p)[i]);
}

// async global->LDS, 16B per lane; LDS dest = wave-uniform base + lane*16
__device__ __forceinline__ void gload16(const u16* g, u16* l) {
    __builtin_amdgcn_global_load_lds(
        (const __attribute__((address_space(1))) unsigned int*)g,
        (__attribute__((address_space(3))) unsigned int*)l, 16, 0, 0);
}

// ---- dtype detect: if buffer is fp32, even-index u16s are mantissa-low garbage ----
__global__ void detect_kernel(const void* x, int* flag)
{
    __shared__ int bad;
    if (threadIdx.x == 0) bad = 0;
    __syncthreads();
    const u16* p = (const u16*)x;
    int local = 0;
    for (int i = threadIdx.x; i < 2048; i += 256) {
        const float v = bf2f(p[2 * i]);
        if (!(fabsf(v) < 1e4f)) local = 1;
    }
    if (local) atomicOr(&bad, 1);
    __syncthreads();
    if (threadIdx.x == 0) *flag = bad;       // 1 => inputs are fp32
}

// ---- fused weight transpose: 4 jobs in one launch, 64x64 LDS tiles ----
__global__ __launch_bounds__(256) void transpose_all_kernel(
    const void* __restrict__ W_in, const void* __restrict__ W_xp,
    const void* __restrict__ W_dt, const void* __restrict__ W_out,
    u16* __restrict__ WtIn, u16* __restrict__ WtXp,
    u16* __restrict__ WtDt, u16* __restrict__ WtOut,
    const int* __restrict__ flagp)
{
    const bool f32 = (*flagp != 0);
    int bid = blockIdx.x;
    const void* src; u16* dst; int K, N, bx, by;
    if (bid < 576)      { src = W_in;  dst = WtIn;  K = 768;  N = 3072; bx = bid % 48; by = bid / 48; }
    else if (bid < 624) { bid -= 576; src = W_xp;  dst = WtXp;  K = 1536; N = 128;  bx = bid % 2;  by = bid / 2; }
    else if (bid < 672) { bid -= 624; src = W_dt;  dst = WtDt;  K = 96;   N = 1536; bx = bid % 24; by = bid / 24; }
    else                { bid -= 672; src = W_out; dst = WtOut; K = 1536; N = 768;  bx = bid % 12; by = bid / 12; }
    __shared__ u16 tile[64][72];
    const int t  = threadIdx.x;
    const int n0 = bx * 64, k0 = by * 64;
    {
        const int r = t >> 2, c = (t & 3) * 16;     // tile-local (k, n)
        const int k = k0 + r;
        if (k < K) {
            #pragma unroll
            for (int i = 0; i < 16; ++i)
                tile[r][c + i] = f2bf(ldx(src, (size_t)k * N + n0 + c + i, f32));
        }
    }
    __syncthreads();
    {
        const int nl = t >> 2, kl = (t & 3) * 16;   // tile-local (n, k)
        const int n = n0 + nl;
        #pragma unroll
        for (int i = 0; i < 16; ++i) {
            const int k = k0 + kl + i;
            if (k < K) dst[(size_t)n * K + k] = tile[kl + i][nl];
        }
    }
}

// ---------------- LayerNorm: x (T,768) -> xn (T,768) bf16 ----------------
__global__ __launch_bounds__(256) void ln_kernel(const void* __restrict__ x,
    const void* __restrict__ g, const void* __restrict__ b, u16* __restrict__ xn,
    const int* __restrict__ flagp)
{
    const bool f32 = (*flagp != 0);
    const int tok = blockIdx.x;
    const int tid = threadIdx.x;
    const size_t base = (size_t)tok * D_MODEL;
    float v[3];
    v[0] = ldx(x, base + tid, f32);
    v[1] = ldx(x, base + tid + 256, f32);
    v[2] = ldx(x, base + tid + 512, f32);
    float s = v[0] + v[1] + v[2];
    float q = v[0]*v[0] + v[1]*v[1] + v[2]*v[2];
    #pragma unroll
    for (int o = 32; o > 0; o >>= 1) {
        s += __shfl_down(s, o, 64);
        q += __shfl_down(q, o, 64);
    }
    __shared__ float ss[4], qq[4];
    if ((tid & 63) == 0) { ss[tid >> 6] = s; qq[tid >> 6] = q; }
    __syncthreads();
    const float S = ss[0] + ss[1] + ss[2] + ss[3];
    const float Q = qq[0] + qq[1] + qq[2] + qq[3];
    const float mu  = S * (1.f / D_MODEL);
    const float var = Q * (1.f / D_MODEL) - mu * mu;
    const float rs  = rsqrtf(var + 1e-5f);
    u16* outr = xn + base;
    #pragma unroll
    for (int i = 0; i < 3; ++i) {
        const int c = tid + i * 256;
        outr[c] = f2bf((v[i] - mu) * rs * ldx(g, c, f32) + ldx(b, c, f32));
    }
}

// ------- MFMA GEMM 64x64 tile, BK=32, 4 waves; A (M,K) bf16, Bt (N,K) bf16 -------
// global_load_lds width-16 staging into linear [64][32] LDS (m97 structure).
// EPI 1: softplus(acc+bias[col]). EPI 2: + res[idx] (flex), flex store.
// EPI 3: atomicAdd fp32 (split-K).
template<int EPI>
__global__ __launch_bounds__(256) void mfma_gemm(
    const u16* __restrict__ A, const u16* __restrict__ Bt,
    u16* __restrict__ C, void* __restrict__ Cout, const void* __restrict__ aux,
    float* __restrict__ Cf, const int* __restrict__ flagp,
    int Kslice, int lda, int ldbt, int ldc)
{
    const bool f32 = (*flagp != 0);
    __shared__ alignas(16) u16 As[64 * 32];
    __shared__ alignas(16) u16 Bs[64 * 32];
    const int tid  = threadIdx.x;
    const int wave = tid >> 6, lane = tid & 63;
    const int lrow = lane & 15, quad = lane >> 4;
    const int row0 = blockIdx.y * 64, col0 = blockIdx.x * 64;
    const int k0   = blockIdx.z * Kslice;
    // staging: wave w owns rows [w*16, w*16+16); lane l -> row w*16+(l>>2), k (l&3)*8
    const int srow = wave * 16 + (lane >> 2);
    const int skk  = (lane & 3) * 8;
    u16* lA = &As[wave * 512];                 // wave-uniform 1KB block base
    u16* lB = &Bs[wave * 512];
    const u16* gA = A  + (size_t)(row0 + srow) * lda  + skk;
    const u16* gB = Bt + (size_t)(col0 + srow) * ldbt + skk;
    f32x4 acc[4] = {{0.f,0.f,0.f,0.f},{0.f,0.f,0.f,0.f},{0.f,0.f,0.f,0.f},{0.f,0.f,0.f,0.f}};
    for (int kt = k0; kt < k0 + Kslice; kt += 32) {
        gload16(gA + kt, lA);
        gload16(gB + kt, lB);
        __syncthreads();
        const bf16x8 af = *(const bf16x8*)(&As[(wave * 16 + lrow) * 32 + quad * 8]);
        #pragma unroll
        for (int t = 0; t < 4; ++t) {
            const bf16x8 bf_ = *(const bf16x8*)(&Bs[(t * 16 + lrow) * 32 + quad * 8]);
            acc[t] = __builtin_amdgcn_mfma_f32_16x16x32_bf16(af, bf_, acc[t], 0, 0, 0);
        }
        __syncthreads();
    }
    #pragma unroll
    for (int t = 0; t < 4; ++t) {
        #pragma unroll
        for (int r = 0; r < 4; ++r) {
            const int row = row0 + wave * 16 + quad * 4 + r;   // C/D: row=quad*4+reg
            const int col = col0 + t * 16 + lrow;              //      col=lane&15
            const size_t idx = (size_t)row * ldc + col;
            float vv = acc[t][r];
            if (EPI == 1) {
                vv += ldx(aux, col, f32);
                vv = (vv > 20.f) ? vv : log1pf(__expf(vv));
                C[idx] = f2bf(vv);
            } else if (EPI == 2) {
                vv += ldx(aux, idx, f32);
                if (f32) ((float*)Cout)[idx] = vv;
                else     ((u16*)Cout)[idx]   = f2bf(vv);
            } else if (EPI == 3) {
                atomicAdd(&Cf[idx], vv);
            } else {
                C[idx] = f2bf(vv);
            }
        }
    }
}

// ------- MFMA GEMM 128x128 tile, BK=32, 4 waves (2x2) -------
// global_load_lds width-16 staging into linear [128][32] LDS (m97 structure).
// EPI 0: bf16 store. EPI 1: softplus(acc + bias[col]) bf16 store.
// EPI 2: + res[idx] (flex), flex store to Cout.
template<int EPI>
__global__ __launch_bounds__(256) void mfma_gemm128(
    const u16* __restrict__ A, const u16* __restrict__ Bt,
    u16* __restrict__ C, void* __restrict__ Cout, const void* __restrict__ aux,
    const int* __restrict__ flagp,
    int K, int lda, int ldbt, int ldc)
{
    const bool f32 = (*flagp != 0);
    __shared__ alignas(16) u16 As[128 * 32];
    __shared__ alignas(16) u16 Bs[128 * 32];
    const int tid  = threadIdx.x;
    const int wave = tid >> 6, lane = tid & 63;
    const int lrow = lane & 15, quad = lane >> 4;
    const int wy = wave >> 1, wx = wave & 1;
    const int row0 = blockIdx.y * 128, col0 = blockIdx.x * 128;
    // staging: 8x 1KB blocks per matrix; wave w owns blocks w and w+4.
    const int skk = (lane & 3) * 8;
    const int r0 = wave * 16 + (lane >> 2);
    const int r1 = r0 + 64;
    u16* lA0 = &As[wave * 512];
    u16* lA1 = &As[(wave + 4) * 512];
    u16* lB0 = &Bs[wave * 512];
    u16* lB1 = &Bs[(wave + 4) * 512];
    const u16* gA0 = A  + (size_t)(row0 + r0) * lda  + skk;
    const u16* gA1 = A  + (size_t)(row0 + r1) * lda  + skk;
    const u16* gB0 = Bt + (size_t)(col0 + r0) * ldbt + skk;
    const u16* gB1 = Bt + (size_t)(col0 + r1) * ldbt + skk;
    f32x4 acc[4][4];
    #pragma unroll
    for (int i = 0; i < 4; ++i)
        #pragma unroll
        for (int j = 0; j < 4; ++j) acc[i][j] = (f32x4){0.f,0.f,0.f,0.f};
    for (int kt = 0; kt < K; kt += 32) {
        gload16(gA0 + kt, lA0);
        gload16(gA1 + kt, lA1);
        gload16(gB0 + kt, lB0);
        gload16(gB1 + kt, lB1);
        __syncthreads();
        bf16x8 af[4], bf_[4];
        #pragma unroll
        for (int i = 0; i < 4; ++i)
            af[i] = *(const bf16x8*)(&As[(wy * 64 + i * 16 + lrow) * 32 + quad * 8]);
        #pragma unroll
        for (int j = 0; j < 4; ++j)
            bf_[j] = *(const bf16x8*)(&Bs[(wx * 64 + j * 16 + lrow) * 32 + quad * 8]);
        #pragma unroll
        for (int i = 0; i < 4; ++i)
            #pragma unroll
            for (int j = 0; j < 4; ++j)
                acc[i][j] = __builtin_amdgcn_mfma_f32_16x16x32_bf16(af[i], bf_[j], acc[i][j], 0, 0, 0);
        __syncthreads();
    }
    #pragma unroll
    for (int i = 0; i < 4; ++i) {
        #pragma unroll
        for (int j = 0; j < 4; ++j) {
            #pragma unroll
            for (int r = 0; r < 4; ++r) {
                const int row = row0 + wy * 64 + i * 16 + quad * 4 + r;
                const int col = col0 + wx * 64 + j * 16 + lrow;
                const size_t idx = (size_t)row * ldc + col;
                float vv = acc[i][j][r];
                if (EPI == 1) {
                    vv += ldx(aux, col, f32);
                    vv = (vv > 20.f) ? vv : log1pf(__expf(vv));
                    C[idx] = f2bf(vv);
                } else if (EPI == 2) {
                    vv += ldx(aux, idx, f32);
                    if (f32) ((float*)Cout)[idx] = vv;
                    else     ((u16*)Cout)[idx]   = f2bf(vv);
                } else {
                    C[idx] = f2bf(vv);
                }
            }
        }
    }
}

// -------- split-K finalize: xdbl = bf16(xdblF) --------
__global__ __launch_bounds__(256) void convert_kernel(const float* __restrict__ src,
                                                      u16* __restrict__ dst, int n)
{
    const int i = blockIdx.x * 256 + threadIdx.x;
    if (i < n) dst[i] = f2bf(src[i]);
}

// ---- causal depthwise conv (width 4, left-pad 3) + SiLU: uv[:, :1536] -> us ----
__global__ __launch_bounds__(256) void conv_silu_kernel(
    const u16* __restrict__ uv, const void* __restrict__ cw, const void* __restrict__ cb,
    u16* __restrict__ us, const int* __restrict__ flagp)
{
    const bool f32 = (*flagp != 0);
    const int idx = blockIdx.x * 256 + threadIdx.x;
    const int d   = idx % D_INNER;
    const int tok = idx / D_INNER;
    const int l   = tok & (LL - 1);
    float acc = ldx(cb, d, f32);
    #pragma unroll
    for (int j = 0; j < 4; ++j) {
        const int li = l - 3 + j;
        if (li >= 0)
            acc += bf2f(uv[(size_t)(tok - 3 + j) * (2*D_INNER) + d]) * ldx(cw, d * 4 + j, f32);
    }
    us[idx] = f2bf(acc / (1.f + __expf(-acc)));
}

// ----- scan pass 1: per-chunk local scan -> carries; one thread owns a full d -----
// a_j = a_1^(j+1) when A2[j] = (j+1)*A2[0] (Mamba A-init) -> 1 exp2 + 15 muls per t.
__global__ __launch_bounds__(256) void scan1_kernel(
    const u16* __restrict__ delta, const u16* __restrict__ us,
    const u16* __restrict__ xdbl, const void* __restrict__ log_A,
    float* __restrict__ carryA, float* __restrict__ carryH,
    const int* __restrict__ flagp)
{
    const bool f32 = (*flagp != 0);
    const int d = blockIdx.x * 256 + threadIdx.x;
    const int c = blockIdx.y, b = blockIdx.z;
    float A2[16], h[16];
    #pragma unroll
    for (int j = 0; j < 16; ++j) {
        A2[j] = -__expf(ldx(log_A, d * D_STATE + j, f32)) * LOG2E;
        h[j] = 0.f;
    }
    bool pw = true;
    #pragma unroll
    for (int j = 1; j < 16; ++j)
        pw = pw && (fabsf(A2[j] - (j + 1) * A2[0]) <= 0.02f * (j + 1) * fabsf(A2[0]));
    float sdl = 0.f;
    size_t tok = (size_t)b * LL + c * CL;
    if (pw) {
        #pragma unroll 2
        for (int t = 0; t < CL; ++t, ++tok) {
            const float dl = bf2f(delta[tok * D_INNER + d]);
            const float ul = bf2f(us[tok * D_INNER + d]);
            const uint4 B0 = *(const uint4*)(xdbl + tok * 128 + DT_RANK);
            const uint4 B1 = *(const uint4*)(xdbl + tok * 128 + DT_RANK + 8);
            const float dlul = dl * ul;
            sdl += dl;
            const unsigned int bw[8] = {B0.x,B0.y,B0.z,B0.w,B1.x,B1.y,B1.z,B1.w};
            const float a1 = exp2f(dl * A2[0]);
            float aj = 1.f;
            #pragma unroll
            for (int j = 0; j < 16; ++j) {
                aj *= a1;
                const float Bn = (j & 1) ? bfu_hi(bw[j >> 1]) : bfu_lo(bw[j >> 1]);
                h[j] = aj * h[j] + dlul * Bn;
            }
        }
    } else {
        #pragma unroll 2
        for (int t = 0; t < CL; ++t, ++tok) {
            const float dl = bf2f(delta[tok * D_INNER + d]);
            const float ul = bf2f(us[tok * D_INNER + d]);
            const uint4 B0 = *(const uint4*)(xdbl + tok * 128 + DT_RANK);
            const uint4 B1 = *(const uint4*)(xdbl + tok * 128 + DT_RANK + 8);
            const float dlul = dl * ul;
            sdl += dl;
            const unsigned int bw[8] = {B0.x,B0.y,B0.z,B0.w,B1.x,B1.y,B1.z,B1.w};
            #pragma unroll
            for (int j = 0; j < 16; ++j) {
                const float Bn = (j & 1) ? bfu_hi(bw[j >> 1]) : bfu_lo(bw[j >> 1]);
                h[j] = exp2f(dl * A2[j]) * h[j] + dlul * Bn;
            }
        }
    }
    const size_t ci = (((size_t)b * NC + c) * D_INNER + d) * D_STATE;
    #pragma unroll
    for (int q = 0; q < 4; ++q) {
        *(float4*)(carryA + ci + 4*q) = (float4){
            exp2f(A2[4*q+0]*sdl), exp2f(A2[4*q+1]*sdl),
            exp2f(A2[4*q+2]*sdl), exp2f(A2[4*q+3]*sdl)};
        *(float4*)(carryH + ci + 4*q) = (float4){h[4*q+0], h[4*q+1], h[4*q+2], h[4*q+3]};
    }
}

// -------- scan pass 2: exclusive scan over chunk carries, in place on carryH --------
__global__ __launch_bounds__(256) void scan2_kernel(
    const float* __restrict__ carryA, float* __restrict__ carryH)
{
    const int gid = blockIdx.x * 256 + threadIdx.x;
    const int b   = gid / (D_INNER * D_STATE);
    const int dn  = gid % (D_INNER * D_STATE);
    float hrun = 0.f;
    #pragma unroll
    for (int c = 0; c < NC; ++c) {
        const size_t ci = ((size_t)(b * NC + c) * D_INNER * D_STATE) + dn;
        const float a = carryA[ci], hh = carryH[ci];
        carryH[ci] = hrun;
        hrun = a * hrun + hh;
    }
}

// ------ scan pass 3: re-run chunk seeded with carry; emit gated y; full-d threads ------
__global__ __launch_bounds__(256) void scan3_kernel(
    const u16* __restrict__ delta, const u16* __restrict__ us,
    const u16* __restrict__ xdbl, u16* __restrict__ uv,
    const void* __restrict__ log_A, const void* __restrict__ D_param,
    const float* __restrict__ carryH, const int* __restrict__ flagp)
{
    const bool f32 = (*flagp != 0);
    const int d = blockIdx.x * 256 + threadIdx.x;
    const int c = blockIdx.y, b = blockIdx.z;
    const float Dd = ldx(D_param, d, f32);
    float A2[16], h[16];
    const size_t ci = (((size_t)b * NC + c) * D_INNER + d) * D_STATE;
    #pragma unroll
    for (int j = 0; j < 16; ++j)
        A2[j] = -__expf(ldx(log_A, d * D_STATE + j, f32)) * LOG2E;
    bool pw = true;
    #pragma unroll
    for (int j = 1; j < 16; ++j)
        pw = pw && (fabsf(A2[j] - (j + 1) * A2[0]) <= 0.02f * (j + 1) * fabsf(A2[0]));
    #pragma unroll
    for (int q = 0; q < 4; ++q) {
        const float4 hq = *(const float4*)(carryH + ci + 4*q);
        h[4*q+0] = hq.x; h[4*q+1] = hq.y; h[4*q+2] = hq.z; h[4*q+3] = hq.w;
    }
    size_t tok = (size_t)b * LL + c * CL;
    if (pw) {
        #pragma unroll 2
        for (int t = 0; t < CL; ++t, ++tok) {
            const float dl = bf2f(delta[tok * D_INNER + d]);
            const float ul = bf2f(us[tok * D_INNER + d]);
            const uint4 B0 = *(const uint4*)(xdbl + tok * 128 + DT_RANK);
            const uint4 B1 = *(const uint4*)(xdbl + tok * 128 + DT_RANK + 8);
            const uint4 C0 = *(const uint4*)(xdbl + tok * 128 + DT_RANK + D_STATE);
            const uint4 C1 = *(const uint4*)(xdbl + tok * 128 + DT_RANK + D_STATE + 8);
            const float dlul = dl * ul;
            const unsigned int bw[8] = {B0.x,B0.y,B0.z,B0.w,B1.x,B1.y,B1.z,B1.w};
            const unsigned int cw_[8] = {C0.x,C0.y,C0.z,C0.w,C1.x,C1.y,C1.z,C1.w};
            const float a1 = exp2f(dl * A2[0]);
            float aj = 1.f, p = 0.f;
            #pragma unroll
            for (int j = 0; j < 16; ++j) {
                aj *= a1;
                const float Bn = (j & 1) ? bfu_hi(bw[j >> 1]) : bfu_lo(bw[j >> 1]);
                const float Cn = (j & 1) ? bfu_hi(cw_[j >> 1]) : bfu_lo(cw_[j >> 1]);
                h[j] = aj * h[j] + dlul * Bn;
                p += h[j] * Cn;
            }
            const float vv = bf2f(uv[tok * (2*D_INNER) + D_INNER + d]);
            uv[tok * (2*D_INNER) + d] = f2bf((p + ul * Dd) * (vv / (1.f + __expf(-vv))));
        }
    } else {
        #pragma unroll 2
        for (int t = 0; t < CL; ++t, ++tok) {
            const float dl = bf2f(delta[tok * D_INNER + d]);
            const float ul = bf2f(us[tok * D_INNER + d]);
            const uint4 B0 = *(const uint4*)(xdbl + tok * 128 + DT_RANK);
            const uint4 B1 = *(const uint4*)(xdbl + tok * 128 + DT_RANK + 8);
            const uint4 C0 = *(const uint4*)(xdbl + tok * 128 + DT_RANK + D_STATE);
            const uint4 C1 = *(const uint4*)(xdbl + tok * 128 + DT_RANK + D_STATE + 8);
            const float dlul = dl * ul;
            const unsigned int bw[8] = {B0.x,B0.y,B0.z,B0.w,B1.x,B1.y,B1.z,B1.w};
            const unsigned int cw_[8] = {C0.x,C0.y,C0.z,C0.w,C1.x,C1.y,C1.z,C1.w};
            float p = 0.f;
            #pragma unroll
            for (int j = 0; j < 16; ++j) {
                const float Bn = (j & 1) ? bfu_hi(bw[j >> 1]) : bfu_lo(bw[j >> 1]);
                const float Cn = (j & 1) ? bfu_hi(cw_[j >> 1]) : bfu_lo(cw_[j >> 1]);
                h[j] = exp2f(dl * A2[j]) * h[j] + dlul * Bn;
                p += h[j] * Cn;
            }
            const float vv = bf2f(uv[tok * (2*D_INNER) + D_INNER + d]);
            uv[tok * (2*D_INNER) + d] = f2bf((p + ul * Dd) * (vv / (1.f + __expf(-vv))));
        }
    }
}

extern "C" void kernel_launch(void* const* d_in, const int* in_sizes, int n_in,
                              void* d_out, int out_size, void* d_ws, size_t ws_size,
                              hipStream_t stream)
{
    const void* x      = d_in[0];
    const void* ln_g   = d_in[1];
    const void* ln_b   = d_in[2];
    const void* W_in   = d_in[3];
    const void* conv_w = d_in[4];
    const void* conv_b = d_in[5];
    const void* W_xp   = d_in[6];
    const void* W_dt   = d_in[7];
    const void* b_dt   = d_in[8];
    const void* log_A  = d_in[9];
    const void* D_par  = d_in[10];
    const void* W_out  = d_in[11];

    // workspace (~93 MB): flag | xn | uv | us | xdbl | delta | carryH | carryA |
    //                     WtIn | WtXp | WtDt | WtOut | xdblF
    int* flag  = (int*)d_ws;
    u16* ws    = (u16*)((char*)d_ws + 512);
    u16* xn    = ws;
    u16* uv    = xn + (size_t)TT * D_MODEL;
    u16* us    = uv + (size_t)TT * 2 * D_INNER;
    u16* xdbl  = us + (size_t)TT * D_INNER;
    u16* delta = xdbl + (size_t)TT * 128;
    float* carryH = (float*)(delta + (size_t)TT * D_INNER);
    float* carryA = carryH + (size_t)BB * NC * D_INNER * D_STATE;
    u16* WtIn  = (u16*)(carryA + (size_t)BB * NC * D_INNER * D_STATE);
    u16* WtXp  = WtIn  + (size_t)2 * D_INNER * D_MODEL;
    u16* WtDt  = WtXp  + (size_t)(DT_RANK + 2 * D_STATE) * D_INNER;
    u16* WtOut = WtDt  + (size_t)D_INNER * DT_RANK;
    float* xdblF = (float*)(WtOut + (size_t)D_MODEL * D_INNER);

    detect_kernel<<<1, 256, 0, stream>>>(x, flag);
    transpose_all_kernel<<<960, 256, 0, stream>>>(
        W_in, W_xp, W_dt, W_out, WtIn, WtXp, WtDt, WtOut, flag);
    hipMemsetAsync(xdblF, 0, (size_t)TT * 128 * sizeof(float), stream);

    ln_kernel<<<TT, 256, 0, stream>>>(x, ln_g, ln_b, xn, flag);
    // uv = xn @ W_in  (4096x3072, K=768)  [128x128, 768 blocks, gload_lds staging]
    mfma_gemm128<0><<<dim3(2 * D_INNER / 128, TT / 128), 256, 0, stream>>>(
        xn, WtIn, uv, nullptr, nullptr, flag, D_MODEL, D_MODEL, D_MODEL, 2 * D_INNER);
    // us = silu(causal_conv(uv[:, :1536]))
    conv_silu_kernel<<<(TT * D_INNER) / 256, 256, 0, stream>>>(uv, conv_w, conv_b, us, flag);
    // xdbl = us @ W_xproj  (4096x128, K=1536)  [64x64, split-K x4]
    mfma_gemm<3><<<dim3(2, TT / 64, SKK), 256, 0, stream>>>(
        us, WtXp, nullptr, nullptr, nullptr, xdblF, flag,
        D_INNER / SKK, D_INNER, D_INNER, 128);
    convert_kernel<<<(TT * 128 + 255) / 256, 256, 0, stream>>>(xdblF, xdbl, TT * 128);
    // delta = softplus(xdbl[:, :96] @ W_dt + b_dt)  (4096x1536, K=96)
    // [R14: 64x64 tile -> 1536 blocks = 24 waves/CU]
    mfma_gemm<1><<<dim3(D_INNER / 64, TT / 64, 1), 256, 0, stream>>>(
        xdbl, WtDt, delta, nullptr, b_dt, nullptr, flag,
        DT_RANK, 128, DT_RANK, D_INNER);
    // chunked selective scan (full-d threads: 768 blocks per pass)
    scan1_kernel<<<dim3(D_INNER / 256, NC, BB), 256, 0, stream>>>(
        delta, us, xdbl, log_A, carryA, carryH, flag);
    scan2_kernel<<<(BB * D_INNER * D_STATE) / 256, 256, 0, stream>>>(carryA, carryH);
    scan3_kernel<<<dim3(D_INNER / 256, NC, BB), 256, 0, stream>>>(
        delta, us, xdbl, uv, log_A, D_par, carryH, flag);
    // out = y @ W_out + x  (4096x768, K=1536)  [128x128 gload_lds, 192 blocks]
    mfma_gemm128<2><<<dim3(D_MODEL / 128, TT / 128), 256, 0, stream>>>(
        uv, WtOut, nullptr, d_out, x, flag, D_INNER, 2 * D_INNER, D_INNER, D_MODEL);
}

// Round 2
// 322.662 us; speedup vs baseline: 1.0597x; 1.0597x over previous
//
#include <hip/hip_runtime.h>

#define D_MODEL 768
#define D_INNER 1536
#define D_STATE 16
#define DT_RANK 96
#define BB 2
#define LL 2048
#define TT (BB*LL)          // 4096 tokens
#define NC 64               // chunks per sequence
#define CL 32               // chunk length
#define SKK 4               // split-K factor for xdbl GEMM
#define LOG2E 1.44269504f

typedef unsigned short u16;
typedef short bf16x8 __attribute__((ext_vector_type(8)));
typedef unsigned short u16x8 __attribute__((ext_vector_type(8)));
typedef float f32x4  __attribute__((ext_vector_type(4)));

__device__ __forceinline__ float bf2f(u16 u) {
    union { unsigned int i; float f; } c; c.i = ((unsigned int)u) << 16; return c.f;
}
__device__ __forceinline__ u16 f2bf(float f) {
    union { float f; unsigned int i; } c; c.f = f;
    unsigned int x = c.i;
    return (u16)((x + 0x7fffu + ((x >> 16) & 1u)) >> 16);   // RNE
}
__device__ __forceinline__ float bfu_lo(unsigned int u) {
    union { unsigned int i; float f; } c; c.i = u << 16; return c.f;
}
__device__ __forceinline__ float bfu_hi(unsigned int u) {
    union { unsigned int i; float f; } c; c.i = u & 0xFFFF0000u; return c.f;
}
__device__ __forceinline__ float ldx(const void* p, size_t i, bool f32) {
    return f32 ? ((const float*)p)[i] : bf2f(((const u16*)p)[i]);
}

// async global->LDS, 16B per lane; LDS dest = wave-uniform base + lane*16
__device__ __forceinline__ void gload16(const u16* g, u16* l) {
    __builtin_amdgcn_global_load_lds(
        (const __attribute__((address_space(1))) unsigned int*)g,
        (__attribute__((address_space(3))) unsigned int*)l, 16, 0, 0);
}

// ---- dtype detect: if buffer is fp32, even-index u16s are mantissa-low garbage ----
__global__ void detect_kernel(const void* x, int* flag)
{
    __shared__ int bad;
    if (threadIdx.x == 0) bad = 0;
    __syncthreads();
    const u16* p = (const u16*)x;
    int local = 0;
    for (int i = threadIdx.x; i < 2048; i += 256) {
        const float v = bf2f(p[2 * i]);
        if (!(fabsf(v) < 1e4f)) local = 1;
    }
    if (local) atomicOr(&bad, 1);
    __syncthreads();
    if (threadIdx.x == 0) *flag = bad;       // 1 => inputs are fp32
}

// ---- fused weight transpose: 4 jobs in one launch, 64x64 LDS tiles ----
__global__ __launch_bounds__(256) void transpose_all_kernel(
    const void* __restrict__ W_in, const void* __restrict__ W_xp,
    const void* __restrict__ W_dt, const void* __restrict__ W_out,
    u16* __restrict__ WtIn, u16* __restrict__ WtXp,
    u16* __restrict__ WtDt, u16* __restrict__ WtOut,
    const int* __restrict__ flagp)
{
    const bool f32 = (*flagp != 0);
    int bid = blockIdx.x;
    const void* src; u16* dst; int K, N, bx, by;
    if (bid < 576)      { src = W_in;  dst = WtIn;  K = 768;  N = 3072; bx = bid % 48; by = bid / 48; }
    else if (bid < 624) { bid -= 576; src = W_xp;  dst = WtXp;  K = 1536; N = 128;  bx = bid % 2;  by = bid / 2; }
    else if (bid < 672) { bid -= 624; src = W_dt;  dst = WtDt;  K = 96;   N = 1536; bx = bid % 24; by = bid / 24; }
    else                { bid -= 672; src = W_out; dst = WtOut; K = 1536; N = 768;  bx = bid % 12; by = bid / 12; }
    __shared__ u16 tile[64][72];
    const int t  = threadIdx.x;
    const int n0 = bx * 64, k0 = by * 64;
    {
        const int r = t >> 2, c = (t & 3) * 16;     // tile-local (k, n)
        const int k = k0 + r;
        if (k < K) {
            #pragma unroll
            for (int i = 0; i < 16; ++i)
                tile[r][c + i] = f2bf(ldx(src, (size_t)k * N + n0 + c + i, f32));
        }
    }
    __syncthreads();
    {
        const int nl = t >> 2, kl = (t & 3) * 16;   // tile-local (n, k)
        const int n = n0 + nl;
        #pragma unroll
        for (int i = 0; i < 16; ++i) {
            const int k = k0 + kl + i;
            if (k < K) dst[(size_t)n * K + k] = tile[kl + i][nl];
        }
    }
}

// ---------------- LayerNorm: x (T,768) -> xn (T,768) bf16 ----------------
__global__ __launch_bounds__(256) void ln_kernel(const void* __restrict__ x,
    const void* __restrict__ g, const void* __restrict__ b, u16* __restrict__ xn,
    const int* __restrict__ flagp)
{
    const bool f32 = (*flagp != 0);
    const int tok = blockIdx.x;
    const int tid = threadIdx.x;
    const size_t base = (size_t)tok * D_MODEL;
    float v[3];
    v[0] = ldx(x, base + tid, f32);
    v[1] = ldx(x, base + tid + 256, f32);
    v[2] = ldx(x, base + tid + 512, f32);
    float s = v[0] + v[1] + v[2];
    float q = v[0]*v[0] + v[1]*v[1] + v[2]*v[2];
    #pragma unroll
    for (int o = 32; o > 0; o >>= 1) {
        s += __shfl_down(s, o, 64);
        q += __shfl_down(q, o, 64);
    }
    __shared__ float ss[4], qq[4];
    if ((tid & 63) == 0) { ss[tid >> 6] = s; qq[tid >> 6] = q; }
    __syncthreads();
    const float S = ss[0] + ss[1] + ss[2] + ss[3];
    const float Q = qq[0] + qq[1] + qq[2] + qq[3];
    const float mu  = S * (1.f / D_MODEL);
    const float var = Q * (1.f / D_MODEL) - mu * mu;
    const float rs  = rsqrtf(var + 1e-5f);
    u16* outr = xn + base;
    #pragma unroll
    for (int i = 0; i < 3; ++i) {
        const int c = tid + i * 256;
        outr[c] = f2bf((v[i] - mu) * rs * ldx(g, c, f32) + ldx(b, c, f32));
    }
}

// ------- MFMA GEMM 64x64 tile, BK=32, 4 waves; A (M,K) bf16, Bt (N,K) bf16 -------
// global_load_lds width-16 staging into linear [64][32] LDS (m97 structure).
// 768-block grids give 3 blocks/CU = 12 waves/CU -> wave-level latency hiding
// (R1 lesson: 128^2 tile at 192 blocks = 7% occupancy, latency-exposed, 55 us).
// EPI 1: softplus(acc+bias[col]). EPI 2: + res[idx] (flex), flex store.
// EPI 3: atomicAdd fp32 (split-K).
template<int EPI>
__global__ __launch_bounds__(256) void mfma_gemm(
    const u16* __restrict__ A, const u16* __restrict__ Bt,
    u16* __restrict__ C, void* __restrict__ Cout, const void* __restrict__ aux,
    float* __restrict__ Cf, const int* __restrict__ flagp,
    int Kslice, int lda, int ldbt, int ldc)
{
    const bool f32 = (*flagp != 0);
    __shared__ alignas(16) u16 As[64 * 32];
    __shared__ alignas(16) u16 Bs[64 * 32];
    const int tid  = threadIdx.x;
    const int wave = tid >> 6, lane = tid & 63;
    const int lrow = lane & 15, quad = lane >> 4;
    const int row0 = blockIdx.y * 64, col0 = blockIdx.x * 64;
    const int k0   = blockIdx.z * Kslice;
    // staging: wave w owns rows [w*16, w*16+16); lane l -> row w*16+(l>>2), k (l&3)*8
    const int srow = wave * 16 + (lane >> 2);
    const int skk  = (lane & 3) * 8;
    u16* lA = &As[wave * 512];                 // wave-uniform 1KB block base
    u16* lB = &Bs[wave * 512];
    const u16* gA = A  + (size_t)(row0 + srow) * lda  + skk;
    const u16* gB = Bt + (size_t)(col0 + srow) * ldbt + skk;
    f32x4 acc[4] = {{0.f,0.f,0.f,0.f},{0.f,0.f,0.f,0.f},{0.f,0.f,0.f,0.f},{0.f,0.f,0.f,0.f}};
    for (int kt = k0; kt < k0 + Kslice; kt += 32) {
        gload16(gA + kt, lA);
        gload16(gB + kt, lB);
        __syncthreads();
        const bf16x8 af = *(const bf16x8*)(&As[(wave * 16 + lrow) * 32 + quad * 8]);
        #pragma unroll
        for (int t = 0; t < 4; ++t) {
            const bf16x8 bf_ = *(const bf16x8*)(&Bs[(t * 16 + lrow) * 32 + quad * 8]);
            acc[t] = __builtin_amdgcn_mfma_f32_16x16x32_bf16(af, bf_, acc[t], 0, 0, 0);
        }
        __syncthreads();
    }
    #pragma unroll
    for (int t = 0; t < 4; ++t) {
        #pragma unroll
        for (int r = 0; r < 4; ++r) {
            const int row = row0 + wave * 16 + quad * 4 + r;   // C/D: row=quad*4+reg
            const int col = col0 + t * 16 + lrow;              //      col=lane&15
            const size_t idx = (size_t)row * ldc + col;
            float vv = acc[t][r];
            if (EPI == 1) {
                vv += ldx(aux, col, f32);
                vv = (vv > 20.f) ? vv : log1pf(__expf(vv));
                C[idx] = f2bf(vv);
            } else if (EPI == 2) {
                vv += ldx(aux, idx, f32);
                if (f32) ((float*)Cout)[idx] = vv;
                else     ((u16*)Cout)[idx]   = f2bf(vv);
            } else if (EPI == 3) {
                atomicAdd(&Cf[idx], vv);
            } else {
                C[idx] = f2bf(vv);
            }
        }
    }
}

// ------- MFMA GEMM 128x128 tile, BK=32, 4 waves (2x2) -------
// global_load_lds width-16 staging into linear [128][32] LDS (m97 structure).
// Use ONLY for grids with >= ~2 blocks/CU (uv GEMM: 768 blocks).
// EPI 0: bf16 store. EPI 1: softplus(acc + bias[col]) bf16 store.
template<int EPI>
__global__ __launch_bounds__(256) void mfma_gemm128(
    const u16* __restrict__ A, const u16* __restrict__ Bt,
    u16* __restrict__ C, void* __restrict__ Cout, const void* __restrict__ aux,
    const int* __restrict__ flagp,
    int K, int lda, int ldbt, int ldc)
{
    const bool f32 = (*flagp != 0);
    __shared__ alignas(16) u16 As[128 * 32];
    __shared__ alignas(16) u16 Bs[128 * 32];
    const int tid  = threadIdx.x;
    const int wave = tid >> 6, lane = tid & 63;
    const int lrow = lane & 15, quad = lane >> 4;
    const int wy = wave >> 1, wx = wave & 1;
    const int row0 = blockIdx.y * 128, col0 = blockIdx.x * 128;
    // staging: 8x 1KB blocks per matrix; wave w owns blocks w and w+4.
    const int skk = (lane & 3) * 8;
    const int r0 = wave * 16 + (lane >> 2);
    const int r1 = r0 + 64;
    u16* lA0 = &As[wave * 512];
    u16* lA1 = &As[(wave + 4) * 512];
    u16* lB0 = &Bs[wave * 512];
    u16* lB1 = &Bs[(wave + 4) * 512];
    const u16* gA0 = A  + (size_t)(row0 + r0) * lda  + skk;
    const u16* gA1 = A  + (size_t)(row0 + r1) * lda  + skk;
    const u16* gB0 = Bt + (size_t)(col0 + r0) * ldbt + skk;
    const u16* gB1 = Bt + (size_t)(col0 + r1) * ldbt + skk;
    f32x4 acc[4][4];
    #pragma unroll
    for (int i = 0; i < 4; ++i)
        #pragma unroll
        for (int j = 0; j < 4; ++j) acc[i][j] = (f32x4){0.f,0.f,0.f,0.f};
    for (int kt = 0; kt < K; kt += 32) {
        gload16(gA0 + kt, lA0);
        gload16(gA1 + kt, lA1);
        gload16(gB0 + kt, lB0);
        gload16(gB1 + kt, lB1);
        __syncthreads();
        bf16x8 af[4], bf_[4];
        #pragma unroll
        for (int i = 0; i < 4; ++i)
            af[i] = *(const bf16x8*)(&As[(wy * 64 + i * 16 + lrow) * 32 + quad * 8]);
        #pragma unroll
        for (int j = 0; j < 4; ++j)
            bf_[j] = *(const bf16x8*)(&Bs[(wx * 64 + j * 16 + lrow) * 32 + quad * 8]);
        #pragma unroll
        for (int i = 0; i < 4; ++i)
            #pragma unroll
            for (int j = 0; j < 4; ++j)
                acc[i][j] = __builtin_amdgcn_mfma_f32_16x16x32_bf16(af[i], bf_[j], acc[i][j], 0, 0, 0);
        __syncthreads();
    }
    #pragma unroll
    for (int i = 0; i < 4; ++i) {
        #pragma unroll
        for (int j = 0; j < 4; ++j) {
            #pragma unroll
            for (int r = 0; r < 4; ++r) {
                const int row = row0 + wy * 64 + i * 16 + quad * 4 + r;
                const int col = col0 + wx * 64 + j * 16 + lrow;
                const size_t idx = (size_t)row * ldc + col;
                float vv = acc[i][j][r];
                if (EPI == 1) {
                    vv += ldx(aux, col, f32);
                    vv = (vv > 20.f) ? vv : log1pf(__expf(vv));
                    C[idx] = f2bf(vv);
                } else if (EPI == 2) {
                    vv += ldx(aux, idx, f32);
                    if (f32) ((float*)Cout)[idx] = vv;
                    else     ((u16*)Cout)[idx]   = f2bf(vv);
                } else {
                    C[idx] = f2bf(vv);
                }
            }
        }
    }
}

// -------- split-K finalize: xdbl = bf16(xdblF) --------
__global__ __launch_bounds__(256) void convert_kernel(const float* __restrict__ src,
                                                      u16* __restrict__ dst, int n)
{
    const int i = blockIdx.x * 256 + threadIdx.x;
    if (i < n) dst[i] = f2bf(src[i]);
}

// ---- causal depthwise conv (width 4, left-pad 3) + SiLU: uv[:, :1536] -> us ----
__global__ __launch_bounds__(256) void conv_silu_kernel(
    const u16* __restrict__ uv, const void* __restrict__ cw, const void* __restrict__ cb,
    u16* __restrict__ us, const int* __restrict__ flagp)
{
    const bool f32 = (*flagp != 0);
    const int idx = blockIdx.x * 256 + threadIdx.x;
    const int d   = idx % D_INNER;
    const int tok = idx / D_INNER;
    const int l   = tok & (LL - 1);
    float acc = ldx(cb, d, f32);
    #pragma unroll
    for (int j = 0; j < 4; ++j) {
        const int li = l - 3 + j;
        if (li >= 0)
            acc += bf2f(uv[(size_t)(tok - 3 + j) * (2*D_INNER) + d]) * ldx(cw, d * 4 + j, f32);
    }
    us[idx] = f2bf(acc / (1.f + __expf(-acc)));
}

// ----- scan pass 1: per-chunk local scan -> carries; one thread owns a full d -----
// a_j = a_1^(j+1) when A2[j] = (j+1)*A2[0] (Mamba A-init) -> 1 exp2 + 15 muls per t.
__global__ __launch_bounds__(256) void scan1_kernel(
    const u16* __restrict__ delta, const u16* __restrict__ us,
    const u16* __restrict__ xdbl, const void* __restrict__ log_A,
    float* __restrict__ carryA, float* __restrict__ carryH,
    const int* __restrict__ flagp)
{
    const bool f32 = (*flagp != 0);
    const int d = blockIdx.x * 256 + threadIdx.x;
    const int c = blockIdx.y, b = blockIdx.z;
    float A2[16], h[16];
    #pragma unroll
    for (int j = 0; j < 16; ++j) {
        A2[j] = -__expf(ldx(log_A, d * D_STATE + j, f32)) * LOG2E;
        h[j] = 0.f;
    }
    bool pw = true;
    #pragma unroll
    for (int j = 1; j < 16; ++j)
        pw = pw && (fabsf(A2[j] - (j + 1) * A2[0]) <= 0.02f * (j + 1) * fabsf(A2[0]));
    float sdl = 0.f;
    size_t tok = (size_t)b * LL + c * CL;
    if (pw) {
        #pragma unroll 2
        for (int t = 0; t < CL; ++t, ++tok) {
            const float dl = bf2f(delta[tok * D_INNER + d]);
            const float ul = bf2f(us[tok * D_INNER + d]);
            const uint4 B0 = *(const uint4*)(xdbl + tok * 128 + DT_RANK);
            const uint4 B1 = *(const uint4*)(xdbl + tok * 128 + DT_RANK + 8);
            const float dlul = dl * ul;
            sdl += dl;
            const unsigned int bw[8] = {B0.x,B0.y,B0.z,B0.w,B1.x,B1.y,B1.z,B1.w};
            const float a1 = exp2f(dl * A2[0]);
            float aj = 1.f;
            #pragma unroll
            for (int j = 0; j < 16; ++j) {
                aj *= a1;
                const float Bn = (j & 1) ? bfu_hi(bw[j >> 1]) : bfu_lo(bw[j >> 1]);
                h[j] = aj * h[j] + dlul * Bn;
            }
        }
    } else {
        #pragma unroll 2
        for (int t = 0; t < CL; ++t, ++tok) {
            const float dl = bf2f(delta[tok * D_INNER + d]);
            const float ul = bf2f(us[tok * D_INNER + d]);
            const uint4 B0 = *(const uint4*)(xdbl + tok * 128 + DT_RANK);
            const uint4 B1 = *(const uint4*)(xdbl + tok * 128 + DT_RANK + 8);
            const float dlul = dl * ul;
            sdl += dl;
            const unsigned int bw[8] = {B0.x,B0.y,B0.z,B0.w,B1.x,B1.y,B1.z,B1.w};
            #pragma unroll
            for (int j = 0; j < 16; ++j) {
                const float Bn = (j & 1) ? bfu_hi(bw[j >> 1]) : bfu_lo(bw[j >> 1]);
                h[j] = exp2f(dl * A2[j]) * h[j] + dlul * Bn;
            }
        }
    }
    const size_t ci = (((size_t)b * NC + c) * D_INNER + d) * D_STATE;
    #pragma unroll
    for (int q = 0; q < 4; ++q) {
        *(float4*)(carryA + ci + 4*q) = (float4){
            exp2f(A2[4*q+0]*sdl), exp2f(A2[4*q+1]*sdl),
            exp2f(A2[4*q+2]*sdl), exp2f(A2[4*q+3]*sdl)};
        *(float4*)(carryH + ci + 4*q) = (float4){h[4*q+0], h[4*q+1], h[4*q+2], h[4*q+3]};
    }
}

// -------- scan pass 2: exclusive scan over chunk carries, in place on carryH --------
__global__ __launch_bounds__(256) void scan2_kernel(
    const float* __restrict__ carryA, float* __restrict__ carryH)
{
    const int gid = blockIdx.x * 256 + threadIdx.x;
    const int b   = gid / (D_INNER * D_STATE);
    const int dn  = gid % (D_INNER * D_STATE);
    float hrun = 0.f;
    #pragma unroll
    for (int c = 0; c < NC; ++c) {
        const size_t ci = ((size_t)(b * NC + c) * D_INNER * D_STATE) + dn;
        const float a = carryA[ci], hh = carryH[ci];
        carryH[ci] = hrun;
        hrun = a * hrun + hh;
    }
}

// ------ scan pass 3: re-run chunk seeded with carry; emit gated y; full-d threads ------
__global__ __launch_bounds__(256) void scan3_kernel(
    const u16* __restrict__ delta, const u16* __restrict__ us,
    const u16* __restrict__ xdbl, u16* __restrict__ uv,
    const void* __restrict__ log_A, const void* __restrict__ D_param,
    const float* __restrict__ carryH, const int* __restrict__ flagp)
{
    const bool f32 = (*flagp != 0);
    const int d = blockIdx.x * 256 + threadIdx.x;
    const int c = blockIdx.y, b = blockIdx.z;
    const float Dd = ldx(D_param, d, f32);
    float A2[16], h[16];
    const size_t ci = (((size_t)b * NC + c) * D_INNER + d) * D_STATE;
    #pragma unroll
    for (int j = 0; j < 16; ++j)
        A2[j] = -__expf(ldx(log_A, d * D_STATE + j, f32)) * LOG2E;
    bool pw = true;
    #pragma unroll
    for (int j = 1; j < 16; ++j)
        pw = pw && (fabsf(A2[j] - (j + 1) * A2[0]) <= 0.02f * (j + 1) * fabsf(A2[0]));
    #pragma unroll
    for (int q = 0; q < 4; ++q) {
        const float4 hq = *(const float4*)(carryH + ci + 4*q);
        h[4*q+0] = hq.x; h[4*q+1] = hq.y; h[4*q+2] = hq.z; h[4*q+3] = hq.w;
    }
    size_t tok = (size_t)b * LL + c * CL;
    if (pw) {
        #pragma unroll 2
        for (int t = 0; t < CL; ++t, ++tok) {
            const float dl = bf2f(delta[tok * D_INNER + d]);
            const float ul = bf2f(us[tok * D_INNER + d]);
            const uint4 B0 = *(const uint4*)(xdbl + tok * 128 + DT_RANK);
            const uint4 B1 = *(const uint4*)(xdbl + tok * 128 + DT_RANK + 8);
            const uint4 C0 = *(const uint4*)(xdbl + tok * 128 + DT_RANK + D_STATE);
            const uint4 C1 = *(const uint4*)(xdbl + tok * 128 + DT_RANK + D_STATE + 8);
            const float dlul = dl * ul;
            const unsigned int bw[8] = {B0.x,B0.y,B0.z,B0.w,B1.x,B1.y,B1.z,B1.w};
            const unsigned int cw_[8] = {C0.x,C0.y,C0.z,C0.w,C1.x,C1.y,C1.z,C1.w};
            const float a1 = exp2f(dl * A2[0]);
            float aj = 1.f, p = 0.f;
            #pragma unroll
            for (int j = 0; j < 16; ++j) {
                aj *= a1;
                const float Bn = (j & 1) ? bfu_hi(bw[j >> 1]) : bfu_lo(bw[j >> 1]);
                const float Cn = (j & 1) ? bfu_hi(cw_[j >> 1]) : bfu_lo(cw_[j >> 1]);
                h[j] = aj * h[j] + dlul * Bn;
                p += h[j] * Cn;
            }
            const float vv = bf2f(uv[tok * (2*D_INNER) + D_INNER + d]);
            uv[tok * (2*D_INNER) + d] = f2bf((p + ul * Dd) * (vv / (1.f + __expf(-vv))));
        }
    } else {
        #pragma unroll 2
        for (int t = 0; t < CL; ++t, ++tok) {
            const float dl = bf2f(delta[tok * D_INNER + d]);
            const float ul = bf2f(us[tok * D_INNER + d]);
            const uint4 B0 = *(const uint4*)(xdbl + tok * 128 + DT_RANK);
            const uint4 B1 = *(const uint4*)(xdbl + tok * 128 + DT_RANK + 8);
            const uint4 C0 = *(const uint4*)(xdbl + tok * 128 + DT_RANK + D_STATE);
            const uint4 C1 = *(const uint4*)(xdbl + tok * 128 + DT_RANK + D_STATE + 8);
            const float dlul = dl * ul;
            const unsigned int bw[8] = {B0.x,B0.y,B0.z,B0.w,B1.x,B1.y,B1.z,B1.w};
            const unsigned int cw_[8] = {C0.x,C0.y,C0.z,C0.w,C1.x,C1.y,C1.z,C1.w};
            float p = 0.f;
            #pragma unroll
            for (int j = 0; j < 16; ++j) {
                const float Bn = (j & 1) ? bfu_hi(bw[j >> 1]) : bfu_lo(bw[j >> 1]);
                const float Cn = (j & 1) ? bfu_hi(cw_[j >> 1]) : bfu_lo(cw_[j >> 1]);
                h[j] = exp2f(dl * A2[j]) * h[j] + dlul * Bn;
                p += h[j] * Cn;
            }
            const float vv = bf2f(uv[tok * (2*D_INNER) + D_INNER + d]);
            uv[tok * (2*D_INNER) + d] = f2bf((p + ul * Dd) * (vv / (1.f + __expf(-vv))));
        }
    }
}

extern "C" void kernel_launch(void* const* d_in, const int* in_sizes, int n_in,
                              void* d_out, int out_size, void* d_ws, size_t ws_size,
                              hipStream_t stream)
{
    const void* x      = d_in[0];
    const void* ln_g   = d_in[1];
    const void* ln_b   = d_in[2];
    const void* W_in   = d_in[3];
    const void* conv_w = d_in[4];
    const void* conv_b = d_in[5];
    const void* W_xp   = d_in[6];
    const void* W_dt   = d_in[7];
    const void* b_dt   = d_in[8];
    const void* log_A  = d_in[9];
    const void* D_par  = d_in[10];
    const void* W_out  = d_in[11];

    // workspace (~93 MB): flag | xn | uv | us | xdbl | delta | carryH | carryA |
    //                     WtIn | WtXp | WtDt | WtOut | xdblF
    int* flag  = (int*)d_ws;
    u16* ws    = (u16*)((char*)d_ws + 512);
    u16* xn    = ws;
    u16* uv    = xn + (size_t)TT * D_MODEL;
    u16* us    = uv + (size_t)TT * 2 * D_INNER;
    u16* xdbl  = us + (size_t)TT * D_INNER;
    u16* delta = xdbl + (size_t)TT * 128;
    float* carryH = (float*)(delta + (size_t)TT * D_INNER);
    float* carryA = carryH + (size_t)BB * NC * D_INNER * D_STATE;
    u16* WtIn  = (u16*)(carryA + (size_t)BB * NC * D_INNER * D_STATE);
    u16* WtXp  = WtIn  + (size_t)2 * D_INNER * D_MODEL;
    u16* WtDt  = WtXp  + (size_t)(DT_RANK + 2 * D_STATE) * D_INNER;
    u16* WtOut = WtDt  + (size_t)D_INNER * DT_RANK;
    float* xdblF = (float*)(WtOut + (size_t)D_MODEL * D_INNER);

    detect_kernel<<<1, 256, 0, stream>>>(x, flag);
    transpose_all_kernel<<<960, 256, 0, stream>>>(
        W_in, W_xp, W_dt, W_out, WtIn, WtXp, WtDt, WtOut, flag);
    hipMemsetAsync(xdblF, 0, (size_t)TT * 128 * sizeof(float), stream);

    ln_kernel<<<TT, 256, 0, stream>>>(x, ln_g, ln_b, xn, flag);
    // uv = xn @ W_in  (4096x3072, K=768)  [128x128, 768 blocks, gload_lds staging]
    mfma_gemm128<0><<<dim3(2 * D_INNER / 128, TT / 128), 256, 0, stream>>>(
        xn, WtIn, uv, nullptr, nullptr, flag, D_MODEL, D_MODEL, D_MODEL, 2 * D_INNER);
    // us = silu(causal_conv(uv[:, :1536]))
    conv_silu_kernel<<<(TT * D_INNER) / 256, 256, 0, stream>>>(uv, conv_w, conv_b, us, flag);
    // xdbl = us @ W_xproj  (4096x128, K=1536)  [64x64, split-K x4]
    mfma_gemm<3><<<dim3(2, TT / 64, SKK), 256, 0, stream>>>(
        us, WtXp, nullptr, nullptr, nullptr, xdblF, flag,
        D_INNER / SKK, D_INNER, D_INNER, 128);
    convert_kernel<<<(TT * 128 + 255) / 256, 256, 0, stream>>>(xdblF, xdbl, TT * 128);
    // delta = softplus(xdbl[:, :96] @ W_dt + b_dt)  (4096x1536, K=96)
    // [R14: 64x64 tile -> 1536 blocks = 24 waves/CU]
    mfma_gemm<1><<<dim3(D_INNER / 64, TT / 64, 1), 256, 0, stream>>>(
        xdbl, WtDt, delta, nullptr, b_dt, nullptr, flag,
        DT_RANK, 128, DT_RANK, D_INNER);
    // chunked selective scan (full-d threads: 768 blocks per pass)
    scan1_kernel<<<dim3(D_INNER / 256, NC, BB), 256, 0, stream>>>(
        delta, us, xdbl, log_A, carryA, carryH, flag);
    scan2_kernel<<<(BB * D_INNER * D_STATE) / 256, 256, 0, stream>>>(carryA, carryH);
    scan3_kernel<<<dim3(D_INNER / 256, NC, BB), 256, 0, stream>>>(
        delta, us, xdbl, uv, log_A, D_par, carryH, flag);
    // out = y @ W_out + x  (4096x768, K=1536)  [64x64 gload_lds, 768 blocks = 3/CU]
    mfma_gemm<2><<<dim3(D_MODEL / 64, TT / 64, 1), 256, 0, stream>>>(
        uv, WtOut, nullptr, d_out, x, nullptr, flag,
        D_INNER, 2 * D_INNER, D_INNER, D_MODEL);
}

// Round 3
// 320.070 us; speedup vs baseline: 1.0683x; 1.0081x over previous
//
#include <hip/hip_runtime.h>

#define D_MODEL 768
#define D_INNER 1536
#define D_STATE 16
#define DT_RANK 96
#define BB 2
#define LL 2048
#define TT (BB*LL)          // 4096 tokens
#define NC 64               // chunks per sequence
#define CL 32               // chunk length
#define SKK 4               // split-K factor for xdbl GEMM
#define LOG2E 1.44269504f

typedef unsigned short u16;
typedef short bf16x8 __attribute__((ext_vector_type(8)));
typedef unsigned short u16x8 __attribute__((ext_vector_type(8)));
typedef float f32x4  __attribute__((ext_vector_type(4)));

__device__ __forceinline__ float bf2f(u16 u) {
    union { unsigned int i; float f; } c; c.i = ((unsigned int)u) << 16; return c.f;
}
__device__ __forceinline__ u16 f2bf(float f) {
    union { float f; unsigned int i; } c; c.f = f;
    unsigned int x = c.i;
    return (u16)((x + 0x7fffu + ((x >> 16) & 1u)) >> 16);   // RNE
}
__device__ __forceinline__ float bfu_lo(unsigned int u) {
    union { unsigned int i; float f; } c; c.i = u << 16; return c.f;
}
__device__ __forceinline__ float bfu_hi(unsigned int u) {
    union { unsigned int i; float f; } c; c.i = u & 0xFFFF0000u; return c.f;
}
__device__ __forceinline__ float ldx(const void* p, size_t i, bool f32) {
    return f32 ? ((const float*)p)[i] : bf2f(((const u16*)p)[i]);
}

// async global->LDS, 16B per lane; LDS dest = wave-uniform base + lane*16
__device__ __forceinline__ void gload16(const u16* g, u16* l) {
    __builtin_amdgcn_global_load_lds(
        (const __attribute__((address_space(1))) unsigned int*)g,
        (__attribute__((address_space(3))) unsigned int*)l, 16, 0, 0);
}

// XCD-aware bijective block swizzle (T1): grids here always have nwg%8==0.
// Gives each XCD a contiguous band of work-ids -> same-row blocks share one L2.
__device__ __forceinline__ void xcd_swz(int& bx, int& by) {
    const int gx = gridDim.x;
    const int cpx = (gx * gridDim.y) >> 3;
    const int bid = by * gx + bx;
    const int w = (bid & 7) * cpx + (bid >> 3);
    bx = w % gx; by = w / gx;
}

// ---- dtype detect: if buffer is fp32, even-index u16s are mantissa-low garbage ----
__global__ void detect_kernel(const void* x, int* flag)
{
    __shared__ int bad;
    if (threadIdx.x == 0) bad = 0;
    __syncthreads();
    const u16* p = (const u16*)x;
    int local = 0;
    for (int i = threadIdx.x; i < 2048; i += 256) {
        const float v = bf2f(p[2 * i]);
        if (!(fabsf(v) < 1e4f)) local = 1;
    }
    if (local) atomicOr(&bad, 1);
    __syncthreads();
    if (threadIdx.x == 0) *flag = bad;       // 1 => inputs are fp32
}

// ---- fused weight transpose: 4 jobs in one launch, 64x64 LDS tiles ----
__global__ __launch_bounds__(256) void transpose_all_kernel(
    const void* __restrict__ W_in, const void* __restrict__ W_xp,
    const void* __restrict__ W_dt, const void* __restrict__ W_out,
    u16* __restrict__ WtIn, u16* __restrict__ WtXp,
    u16* __restrict__ WtDt, u16* __restrict__ WtOut,
    const int* __restrict__ flagp)
{
    const bool f32 = (*flagp != 0);
    int bid = blockIdx.x;
    const void* src; u16* dst; int K, N, bx, by;
    if (bid < 576)      { src = W_in;  dst = WtIn;  K = 768;  N = 3072; bx = bid % 48; by = bid / 48; }
    else if (bid < 624) { bid -= 576; src = W_xp;  dst = WtXp;  K = 1536; N = 128;  bx = bid % 2;  by = bid / 2; }
    else if (bid < 672) { bid -= 624; src = W_dt;  dst = WtDt;  K = 96;   N = 1536; bx = bid % 24; by = bid / 24; }
    else                { bid -= 672; src = W_out; dst = WtOut; K = 1536; N = 768;  bx = bid % 12; by = bid / 12; }
    __shared__ u16 tile[64][72];
    const int t  = threadIdx.x;
    const int n0 = bx * 64, k0 = by * 64;
    {
        const int r = t >> 2, c = (t & 3) * 16;     // tile-local (k, n)
        const int k = k0 + r;
        if (k < K) {
            #pragma unroll
            for (int i = 0; i < 16; ++i)
                tile[r][c + i] = f2bf(ldx(src, (size_t)k * N + n0 + c + i, f32));
        }
    }
    __syncthreads();
    {
        const int nl = t >> 2, kl = (t & 3) * 16;   // tile-local (n, k)
        const int n = n0 + nl;
        #pragma unroll
        for (int i = 0; i < 16; ++i) {
            const int k = k0 + kl + i;
            if (k < K) dst[(size_t)n * K + k] = tile[kl + i][nl];
        }
    }
}

// ---------------- LayerNorm: x (T,768) -> xn (T,768) bf16 ----------------
__global__ __launch_bounds__(256) void ln_kernel(const void* __restrict__ x,
    const void* __restrict__ g, const void* __restrict__ b, u16* __restrict__ xn,
    const int* __restrict__ flagp)
{
    const bool f32 = (*flagp != 0);
    const int tok = blockIdx.x;
    const int tid = threadIdx.x;
    const size_t base = (size_t)tok * D_MODEL;
    float v[3];
    v[0] = ldx(x, base + tid, f32);
    v[1] = ldx(x, base + tid + 256, f32);
    v[2] = ldx(x, base + tid + 512, f32);
    float s = v[0] + v[1] + v[2];
    float q = v[0]*v[0] + v[1]*v[1] + v[2]*v[2];
    #pragma unroll
    for (int o = 32; o > 0; o >>= 1) {
        s += __shfl_down(s, o, 64);
        q += __shfl_down(q, o, 64);
    }
    __shared__ float ss[4], qq[4];
    if ((tid & 63) == 0) { ss[tid >> 6] = s; qq[tid >> 6] = q; }
    __syncthreads();
    const float S = ss[0] + ss[1] + ss[2] + ss[3];
    const float Q = qq[0] + qq[1] + qq[2] + qq[3];
    const float mu  = S * (1.f / D_MODEL);
    const float var = Q * (1.f / D_MODEL) - mu * mu;
    const float rs  = rsqrtf(var + 1e-5f);
    u16* outr = xn + base;
    #pragma unroll
    for (int i = 0; i < 3; ++i) {
        const int c = tid + i * 256;
        outr[c] = f2bf((v[i] - mu) * rs * ldx(g, c, f32) + ldx(b, c, f32));
    }
}

// ------- MFMA GEMM 64x64 tile, BK=32, 4 waves; A (M,K) bf16, Bt (N,K) bf16 -------
// T3-min 2-phase: double-buffered LDS, stage tile t+1 BEFORE computing tile t,
// ONE barrier per K-step (was 2; load latency was fully exposed).
// T1 XCD swizzle when gridDim.z==1 (all callers have nwg%8==0).
// EPI 1: softplus(acc+bias[col]). EPI 2: + res[idx] (flex), flex store.
// EPI 3: atomicAdd fp32 (split-K).
template<int EPI>
__global__ __launch_bounds__(256) void mfma_gemm(
    const u16* __restrict__ A, const u16* __restrict__ Bt,
    u16* __restrict__ C, void* __restrict__ Cout, const void* __restrict__ aux,
    float* __restrict__ Cf, const int* __restrict__ flagp,
    int Kslice, int lda, int ldbt, int ldc)
{
    const bool f32 = (*flagp != 0);
    __shared__ alignas(16) u16 As[2 * 64 * 32];
    __shared__ alignas(16) u16 Bs[2 * 64 * 32];
    const int tid  = threadIdx.x;
    const int wave = tid >> 6, lane = tid & 63;
    const int lrow = lane & 15, quad = lane >> 4;
    int bx = blockIdx.x, by = blockIdx.y;
    if (gridDim.z == 1) xcd_swz(bx, by);
    const int row0 = by * 64, col0 = bx * 64;
    const int k0   = blockIdx.z * Kslice;
    // staging: wave w owns rows [w*16, w*16+16); lane l -> row w*16+(l>>2), k (l&3)*8
    const int srow = wave * 16 + (lane >> 2);
    const int skk  = (lane & 3) * 8;
    const int wb   = wave * 512;               // wave-uniform 1KB block offset
    const u16* gA = A  + (size_t)(row0 + srow) * lda  + k0 + skk;
    const u16* gB = Bt + (size_t)(col0 + srow) * ldbt + k0 + skk;
    const int nst = Kslice >> 5;
    gload16(gA, &As[wb]);
    gload16(gB, &Bs[wb]);
    f32x4 acc[4] = {{0.f,0.f,0.f,0.f},{0.f,0.f,0.f,0.f},{0.f,0.f,0.f,0.f},{0.f,0.f,0.f,0.f}};
    int cur = 0;
    for (int t = 0; t < nst; ++t) {
        __syncthreads();                       // drains tile-t loads; joins readers of buf cur^1
        const int boff = cur << 11;            // cur * 64*32
        if (t + 1 < nst) {
            const int poff = boff ^ 2048;
            gload16(gA + (t + 1) * 32, &As[poff + wb]);
            gload16(gB + (t + 1) * 32, &Bs[poff + wb]);
        }
        const bf16x8 af = *(const bf16x8*)(&As[boff + (wave * 16 + lrow) * 32 + quad * 8]);
        #pragma unroll
        for (int q = 0; q < 4; ++q) {
            const bf16x8 bq = *(const bf16x8*)(&Bs[boff + (q * 16 + lrow) * 32 + quad * 8]);
            acc[q] = __builtin_amdgcn_mfma_f32_16x16x32_bf16(af, bq, acc[q], 0, 0, 0);
        }
        cur ^= 1;
    }
    #pragma unroll
    for (int t = 0; t < 4; ++t) {
        #pragma unroll
        for (int r = 0; r < 4; ++r) {
            const int row = row0 + wave * 16 + quad * 4 + r;   // C/D: row=quad*4+reg
            const int col = col0 + t * 16 + lrow;              //      col=lane&15
            const size_t idx = (size_t)row * ldc + col;
            float vv = acc[t][r];
            if (EPI == 1) {
                vv += ldx(aux, col, f32);
                vv = (vv > 20.f) ? vv : log1pf(__expf(vv));
                C[idx] = f2bf(vv);
            } else if (EPI == 2) {
                vv += ldx(aux, idx, f32);
                if (f32) ((float*)Cout)[idx] = vv;
                else     ((u16*)Cout)[idx]   = f2bf(vv);
            } else if (EPI == 3) {
                atomicAdd(&Cf[idx], vv);
            } else {
                C[idx] = f2bf(vv);
            }
        }
    }
}

// ------- MFMA GEMM 128x128 tile, BK=32, 4 waves (2x2) -------
// Same 2-phase dbuf + XCD swizzle. Use only for grids >= ~2 blocks/CU.
// EPI 0: bf16 store. EPI 1: softplus(acc + bias[col]) bf16 store.
template<int EPI>
__global__ __launch_bounds__(256) void mfma_gemm128(
    const u16* __restrict__ A, const u16* __restrict__ Bt,
    u16* __restrict__ C, void* __restrict__ Cout, const void* __restrict__ aux,
    const int* __restrict__ flagp,
    int K, int lda, int ldbt, int ldc)
{
    const bool f32 = (*flagp != 0);
    __shared__ alignas(16) u16 As[2 * 128 * 32];
    __shared__ alignas(16) u16 Bs[2 * 128 * 32];
    const int tid  = threadIdx.x;
    const int wave = tid >> 6, lane = tid & 63;
    const int lrow = lane & 15, quad = lane >> 4;
    const int wy = wave >> 1, wx = wave & 1;
    int bx = blockIdx.x, by = blockIdx.y;
    if (gridDim.z == 1) xcd_swz(bx, by);
    const int row0 = by * 128, col0 = bx * 128;
    // staging: 8x 1KB blocks per matrix per buffer; wave w owns blocks w and w+4.
    const int skk = (lane & 3) * 8;
    const int r0 = wave * 16 + (lane >> 2);
    const int r1 = r0 + 64;
    const int wb0 = wave * 512, wb1 = (wave + 4) * 512;
    const u16* gA0 = A  + (size_t)(row0 + r0) * lda  + skk;
    const u16* gA1 = A  + (size_t)(row0 + r1) * lda  + skk;
    const u16* gB0 = Bt + (size_t)(col0 + r0) * ldbt + skk;
    const u16* gB1 = Bt + (size_t)(col0 + r1) * ldbt + skk;
    const int nst = K >> 5;
    gload16(gA0, &As[wb0]);
    gload16(gA1, &As[wb1]);
    gload16(gB0, &Bs[wb0]);
    gload16(gB1, &Bs[wb1]);
    f32x4 acc[4][4];
    #pragma unroll
    for (int i = 0; i < 4; ++i)
        #pragma unroll
        for (int j = 0; j < 4; ++j) acc[i][j] = (f32x4){0.f,0.f,0.f,0.f};
    int cur = 0;
    for (int t = 0; t < nst; ++t) {
        __syncthreads();
        const int boff = cur << 12;            // cur * 128*32
        if (t + 1 < nst) {
            const int poff = boff ^ 4096;
            const int kt = (t + 1) * 32;
            gload16(gA0 + kt, &As[poff + wb0]);
            gload16(gA1 + kt, &As[poff + wb1]);
            gload16(gB0 + kt, &Bs[poff + wb0]);
            gload16(gB1 + kt, &Bs[poff + wb1]);
        }
        bf16x8 af[4], bf_[4];
        #pragma unroll
        for (int i = 0; i < 4; ++i)
            af[i] = *(const bf16x8*)(&As[boff + (wy * 64 + i * 16 + lrow) * 32 + quad * 8]);
        #pragma unroll
        for (int j = 0; j < 4; ++j)
            bf_[j] = *(const bf16x8*)(&Bs[boff + (wx * 64 + j * 16 + lrow) * 32 + quad * 8]);
        #pragma unroll
        for (int i = 0; i < 4; ++i)
            #pragma unroll
            for (int j = 0; j < 4; ++j)
                acc[i][j] = __builtin_amdgcn_mfma_f32_16x16x32_bf16(af[i], bf_[j], acc[i][j], 0, 0, 0);
        cur ^= 1;
    }
    #pragma unroll
    for (int i = 0; i < 4; ++i) {
        #pragma unroll
        for (int j = 0; j < 4; ++j) {
            #pragma unroll
            for (int r = 0; r < 4; ++r) {
                const int row = row0 + wy * 64 + i * 16 + quad * 4 + r;
                const int col = col0 + wx * 64 + j * 16 + lrow;
                const size_t idx = (size_t)row * ldc + col;
                float vv = acc[i][j][r];
                if (EPI == 1) {
                    vv += ldx(aux, col, f32);
                    vv = (vv > 20.f) ? vv : log1pf(__expf(vv));
                    C[idx] = f2bf(vv);
                } else if (EPI == 2) {
                    vv += ldx(aux, idx, f32);
                    if (f32) ((float*)Cout)[idx] = vv;
                    else     ((u16*)Cout)[idx]   = f2bf(vv);
                } else {
                    C[idx] = f2bf(vv);
                }
            }
        }
    }
}

// -------- split-K finalize: xdbl = bf16(xdblF) --------
__global__ __launch_bounds__(256) void convert_kernel(const float* __restrict__ src,
                                                      u16* __restrict__ dst, int n)
{
    const int i = blockIdx.x * 256 + threadIdx.x;
    if (i < n) dst[i] = f2bf(src[i]);
}

// ---- causal depthwise conv (width 4, left-pad 3) + SiLU: uv[:, :1536] -> us ----
__global__ __launch_bounds__(256) void conv_silu_kernel(
    const u16* __restrict__ uv, const void* __restrict__ cw, const void* __restrict__ cb,
    u16* __restrict__ us, const int* __restrict__ flagp)
{
    const bool f32 = (*flagp != 0);
    const int idx = blockIdx.x * 256 + threadIdx.x;
    const int d   = idx % D_INNER;
    const int tok = idx / D_INNER;
    const int l   = tok & (LL - 1);
    float acc = ldx(cb, d, f32);
    #pragma unroll
    for (int j = 0; j < 4; ++j) {
        const int li = l - 3 + j;
        if (li >= 0)
            acc += bf2f(uv[(size_t)(tok - 3 + j) * (2*D_INNER) + d]) * ldx(cw, d * 4 + j, f32);
    }
    us[idx] = f2bf(acc / (1.f + __expf(-acc)));
}

// ----- scan pass 1: per-chunk local scan -> carries; one thread owns a full d -----
// a_j = a_1^(j+1) when A2[j] = (j+1)*A2[0] (Mamba A-init) -> 1 exp2 + 15 muls per t.
__global__ __launch_bounds__(256) void scan1_kernel(
    const u16* __restrict__ delta, const u16* __restrict__ us,
    const u16* __restrict__ xdbl, const void* __restrict__ log_A,
    float* __restrict__ carryA, float* __restrict__ carryH,
    const int* __restrict__ flagp)
{
    const bool f32 = (*flagp != 0);
    const int d = blockIdx.x * 256 + threadIdx.x;
    const int c = blockIdx.y, b = blockIdx.z;
    float A2[16], h[16];
    #pragma unroll
    for (int j = 0; j < 16; ++j) {
        A2[j] = -__expf(ldx(log_A, d * D_STATE + j, f32)) * LOG2E;
        h[j] = 0.f;
    }
    bool pw = true;
    #pragma unroll
    for (int j = 1; j < 16; ++j)
        pw = pw && (fabsf(A2[j] - (j + 1) * A2[0]) <= 0.02f * (j + 1) * fabsf(A2[0]));
    float sdl = 0.f;
    size_t tok = (size_t)b * LL + c * CL;
    if (pw) {
        #pragma unroll 2
        for (int t = 0; t < CL; ++t, ++tok) {
            const float dl = bf2f(delta[tok * D_INNER + d]);
            const float ul = bf2f(us[tok * D_INNER + d]);
            const uint4 B0 = *(const uint4*)(xdbl + tok * 128 + DT_RANK);
            const uint4 B1 = *(const uint4*)(xdbl + tok * 128 + DT_RANK + 8);
            const float dlul = dl * ul;
            sdl += dl;
            const unsigned int bw[8] = {B0.x,B0.y,B0.z,B0.w,B1.x,B1.y,B1.z,B1.w};
            const float a1 = exp2f(dl * A2[0]);
            float aj = 1.f;
            #pragma unroll
            for (int j = 0; j < 16; ++j) {
                aj *= a1;
                const float Bn = (j & 1) ? bfu_hi(bw[j >> 1]) : bfu_lo(bw[j >> 1]);
                h[j] = aj * h[j] + dlul * Bn;
            }
        }
    } else {
        #pragma unroll 2
        for (int t = 0; t < CL; ++t, ++tok) {
            const float dl = bf2f(delta[tok * D_INNER + d]);
            const float ul = bf2f(us[tok * D_INNER + d]);
            const uint4 B0 = *(const uint4*)(xdbl + tok * 128 + DT_RANK);
            const uint4 B1 = *(const uint4*)(xdbl + tok * 128 + DT_RANK + 8);
            const float dlul = dl * ul;
            sdl += dl;
            const unsigned int bw[8] = {B0.x,B0.y,B0.z,B0.w,B1.x,B1.y,B1.z,B1.w};
            #pragma unroll
            for (int j = 0; j < 16; ++j) {
                const float Bn = (j & 1) ? bfu_hi(bw[j >> 1]) : bfu_lo(bw[j >> 1]);
                h[j] = exp2f(dl * A2[j]) * h[j] + dlul * Bn;
            }
        }
    }
    const size_t ci = (((size_t)b * NC + c) * D_INNER + d) * D_STATE;
    #pragma unroll
    for (int q = 0; q < 4; ++q) {
        *(float4*)(carryA + ci + 4*q) = (float4){
            exp2f(A2[4*q+0]*sdl), exp2f(A2[4*q+1]*sdl),
            exp2f(A2[4*q+2]*sdl), exp2f(A2[4*q+3]*sdl)};
        *(float4*)(carryH + ci + 4*q) = (float4){h[4*q+0], h[4*q+1], h[4*q+2], h[4*q+3]};
    }
}

// -------- scan pass 2: exclusive scan over chunk carries, in place on carryH --------
__global__ __launch_bounds__(256) void scan2_kernel(
    const float* __restrict__ carryA, float* __restrict__ carryH)
{
    const int gid = blockIdx.x * 256 + threadIdx.x;
    const int b   = gid / (D_INNER * D_STATE);
    const int dn  = gid % (D_INNER * D_STATE);
    float hrun = 0.f;
    #pragma unroll
    for (int c = 0; c < NC; ++c) {
        const size_t ci = ((size_t)(b * NC + c) * D_INNER * D_STATE) + dn;
        const float a = carryA[ci], hh = carryH[ci];
        carryH[ci] = hrun;
        hrun = a * hrun + hh;
    }
}

// ------ scan pass 3: re-run chunk seeded with carry; emit gated y; full-d threads ------
__global__ __launch_bounds__(256) void scan3_kernel(
    const u16* __restrict__ delta, const u16* __restrict__ us,
    const u16* __restrict__ xdbl, u16* __restrict__ uv,
    const void* __restrict__ log_A, const void* __restrict__ D_param,
    const float* __restrict__ carryH, const int* __restrict__ flagp)
{
    const bool f32 = (*flagp != 0);
    const int d = blockIdx.x * 256 + threadIdx.x;
    const int c = blockIdx.y, b = blockIdx.z;
    const float Dd = ldx(D_param, d, f32);
    float A2[16], h[16];
    const size_t ci = (((size_t)b * NC + c) * D_INNER + d) * D_STATE;
    #pragma unroll
    for (int j = 0; j < 16; ++j)
        A2[j] = -__expf(ldx(log_A, d * D_STATE + j, f32)) * LOG2E;
    bool pw = true;
    #pragma unroll
    for (int j = 1; j < 16; ++j)
        pw = pw && (fabsf(A2[j] - (j + 1) * A2[0]) <= 0.02f * (j + 1) * fabsf(A2[0]));
    #pragma unroll
    for (int q = 0; q < 4; ++q) {
        const float4 hq = *(const float4*)(carryH + ci + 4*q);
        h[4*q+0] = hq.x; h[4*q+1] = hq.y; h[4*q+2] = hq.z; h[4*q+3] = hq.w;
    }
    size_t tok = (size_t)b * LL + c * CL;
    if (pw) {
        #pragma unroll 2
        for (int t = 0; t < CL; ++t, ++tok) {
            const float dl = bf2f(delta[tok * D_INNER + d]);
            const float ul = bf2f(us[tok * D_INNER + d]);
            const uint4 B0 = *(const uint4*)(xdbl + tok * 128 + DT_RANK);
            const uint4 B1 = *(const uint4*)(xdbl + tok * 128 + DT_RANK + 8);
            const uint4 C0 = *(const uint4*)(xdbl + tok * 128 + DT_RANK + D_STATE);
            const uint4 C1 = *(const uint4*)(xdbl + tok * 128 + DT_RANK + D_STATE + 8);
            const float dlul = dl * ul;
            const unsigned int bw[8] = {B0.x,B0.y,B0.z,B0.w,B1.x,B1.y,B1.z,B1.w};
            const unsigned int cw_[8] = {C0.x,C0.y,C0.z,C0.w,C1.x,C1.y,C1.z,C1.w};
            const float a1 = exp2f(dl * A2[0]);
            float aj = 1.f, p = 0.f;
            #pragma unroll
            for (int j = 0; j < 16; ++j) {
                aj *= a1;
                const float Bn = (j & 1) ? bfu_hi(bw[j >> 1]) : bfu_lo(bw[j >> 1]);
                const float Cn = (j & 1) ? bfu_hi(cw_[j >> 1]) : bfu_lo(cw_[j >> 1]);
                h[j] = aj * h[j] + dlul * Bn;
                p += h[j] * Cn;
            }
            const float vv = bf2f(uv[tok * (2*D_INNER) + D_INNER + d]);
            uv[tok * (2*D_INNER) + d] = f2bf((p + ul * Dd) * (vv / (1.f + __expf(-vv))));
        }
    } else {
        #pragma unroll 2
        for (int t = 0; t < CL; ++t, ++tok) {
            const float dl = bf2f(delta[tok * D_INNER + d]);
            const float ul = bf2f(us[tok * D_INNER + d]);
            const uint4 B0 = *(const uint4*)(xdbl + tok * 128 + DT_RANK);
            const uint4 B1 = *(const uint4*)(xdbl + tok * 128 + DT_RANK + 8);
            const uint4 C0 = *(const uint4*)(xdbl + tok * 128 + DT_RANK + D_STATE);
            const uint4 C1 = *(const uint4*)(xdbl + tok * 128 + DT_RANK + D_STATE + 8);
            const float dlul = dl * ul;
            const unsigned int bw[8] = {B0.x,B0.y,B0.z,B0.w,B1.x,B1.y,B1.z,B1.w};
            const unsigned int cw_[8] = {C0.x,C0.y,C0.z,C0.w,C1.x,C1.y,C1.z,C1.w};
            float p = 0.f;
            #pragma unroll
            for (int j = 0; j < 16; ++j) {
                const float Bn = (j & 1) ? bfu_hi(bw[j >> 1]) : bfu_lo(bw[j >> 1]);
                const float Cn = (j & 1) ? bfu_hi(cw_[j >> 1]) : bfu_lo(cw_[j >> 1]);
                h[j] = exp2f(dl * A2[j]) * h[j] + dlul * Bn;
                p += h[j] * Cn;
            }
            const float vv = bf2f(uv[tok * (2*D_INNER) + D_INNER + d]);
            uv[tok * (2*D_INNER) + d] = f2bf((p + ul * Dd) * (vv / (1.f + __expf(-vv))));
        }
    }
}

extern "C" void kernel_launch(void* const* d_in, const int* in_sizes, int n_in,
                              void* d_out, int out_size, void* d_ws, size_t ws_size,
                              hipStream_t stream)
{
    const void* x      = d_in[0];
    const void* ln_g   = d_in[1];
    const void* ln_b   = d_in[2];
    const void* W_in   = d_in[3];
    const void* conv_w = d_in[4];
    const void* conv_b = d_in[5];
    const void* W_xp   = d_in[6];
    const void* W_dt   = d_in[7];
    const void* b_dt   = d_in[8];
    const void* log_A  = d_in[9];
    const void* D_par  = d_in[10];
    const void* W_out  = d_in[11];

    // workspace (~93 MB): flag | xn | uv | us | xdbl | delta | carryH | carryA |
    //                     WtIn | WtXp | WtDt | WtOut | xdblF
    int* flag  = (int*)d_ws;
    u16* ws    = (u16*)((char*)d_ws + 512);
    u16* xn    = ws;
    u16* uv    = xn + (size_t)TT * D_MODEL;
    u16* us    = uv + (size_t)TT * 2 * D_INNER;
    u16* xdbl  = us + (size_t)TT * D_INNER;
    u16* delta = xdbl + (size_t)TT * 128;
    float* carryH = (float*)(delta + (size_t)TT * D_INNER);
    float* carryA = carryH + (size_t)BB * NC * D_INNER * D_STATE;
    u16* WtIn  = (u16*)(carryA + (size_t)BB * NC * D_INNER * D_STATE);
    u16* WtXp  = WtIn  + (size_t)2 * D_INNER * D_MODEL;
    u16* WtDt  = WtXp  + (size_t)(DT_RANK + 2 * D_STATE) * D_INNER;
    u16* WtOut = WtDt  + (size_t)D_INNER * DT_RANK;
    float* xdblF = (float*)(WtOut + (size_t)D_MODEL * D_INNER);

    detect_kernel<<<1, 256, 0, stream>>>(x, flag);
    transpose_all_kernel<<<960, 256, 0, stream>>>(
        W_in, W_xp, W_dt, W_out, WtIn, WtXp, WtDt, WtOut, flag);
    hipMemsetAsync(xdblF, 0, (size_t)TT * 128 * sizeof(float), stream);

    ln_kernel<<<TT, 256, 0, stream>>>(x, ln_g, ln_b, xn, flag);
    // uv = xn @ W_in  (4096x3072, K=768)  [128x128, 768 blocks, dbuf + swizzle]
    mfma_gemm128<0><<<dim3(2 * D_INNER / 128, TT / 128), 256, 0, stream>>>(
        xn, WtIn, uv, nullptr, nullptr, flag, D_MODEL, D_MODEL, D_MODEL, 2 * D_INNER);
    // us = silu(causal_conv(uv[:, :1536]))
    conv_silu_kernel<<<(TT * D_INNER) / 256, 256, 0, stream>>>(uv, conv_w, conv_b, us, flag);
    // xdbl = us @ W_xproj  (4096x128, K=1536)  [64x64, split-K x4, dbuf, no swizzle (z>1)]
    mfma_gemm<3><<<dim3(2, TT / 64, SKK), 256, 0, stream>>>(
        us, WtXp, nullptr, nullptr, nullptr, xdblF, flag,
        D_INNER / SKK, D_INNER, D_INNER, 128);
    convert_kernel<<<(TT * 128 + 255) / 256, 256, 0, stream>>>(xdblF, xdbl, TT * 128);
    // delta = softplus(xdbl[:, :96] @ W_dt + b_dt)  (4096x1536, K=96)
    // [64x64 tile -> 1536 blocks = 24 waves/CU, dbuf + swizzle]
    mfma_gemm<1><<<dim3(D_INNER / 64, TT / 64, 1), 256, 0, stream>>>(
        xdbl, WtDt, delta, nullptr, b_dt, nullptr, flag,
        DT_RANK, 128, DT_RANK, D_INNER);
    // chunked selective scan (full-d threads: 768 blocks per pass)
    scan1_kernel<<<dim3(D_INNER / 256, NC, BB), 256, 0, stream>>>(
        delta, us, xdbl, log_A, carryA, carryH, flag);
    scan2_kernel<<<(BB * D_INNER * D_STATE) / 256, 256, 0, stream>>>(carryA, carryH);
    scan3_kernel<<<dim3(D_INNER / 256, NC, BB), 256, 0, stream>>>(
        delta, us, xdbl, uv, log_A, D_par, carryH, flag);
    // out = y @ W_out + x  (4096x768, K=1536)  [64x64, 768 blocks = 3/CU, dbuf + swizzle]
    mfma_gemm<2><<<dim3(D_MODEL / 64, TT / 64, 1), 256, 0, stream>>>(
        uv, WtOut, nullptr, d_out, x, nullptr, flag,
        D_INNER, 2 * D_INNER, D_INNER, D_MODEL);
}

// Round 4
// 295.226 us; speedup vs baseline: 1.1582x; 1.0842x over previous
//
#include <hip/hip_runtime.h>

#define D_MODEL 768
#define D_INNER 1536
#define D_STATE 16
#define DT_RANK 96
#define BB 2
#define LL 2048
#define TT (BB*LL)          // 4096 tokens
#define NC 64               // chunks per sequence
#define CL 32               // chunk length
#define SKK 4               // split-K factor for xdbl GEMM
#define LOG2E 1.44269504f

typedef unsigned short u16;
typedef short bf16x8 __attribute__((ext_vector_type(8)));
typedef unsigned short u16x8 __attribute__((ext_vector_type(8)));
typedef float f32x4  __attribute__((ext_vector_type(4)));

__device__ __forceinline__ float bf2f(u16 u) {
    union { unsigned int i; float f; } c; c.i = ((unsigned int)u) << 16; return c.f;
}
__device__ __forceinline__ u16 f2bf(float f) {
    union { float f; unsigned int i; } c; c.f = f;
    unsigned int x = c.i;
    return (u16)((x + 0x7fffu + ((x >> 16) & 1u)) >> 16);   // RNE
}
__device__ __forceinline__ float bfu_lo(unsigned int u) {
    union { unsigned int i; float f; } c; c.i = u << 16; return c.f;
}
__device__ __forceinline__ float bfu_hi(unsigned int u) {
    union { unsigned int i; float f; } c; c.i = u & 0xFFFF0000u; return c.f;
}
__device__ __forceinline__ float ldx(const void* p, size_t i, bool f32) {
    return f32 ? ((const float*)p)[i] : bf2f(((const u16*)p)[i]);
}

// async global->LDS, 16B per lane; LDS dest = wave-uniform base + lane*16
__device__ __forceinline__ void gload16(const u16* g, u16* l) {
    __builtin_amdgcn_global_load_lds(
        (const __attribute__((address_space(1))) unsigned int*)g,
        (__attribute__((address_space(3))) unsigned int*)l, 16, 0, 0);
}

// XCD-aware bijective block swizzle (T1): grids here always have nwg%8==0.
__device__ __forceinline__ void xcd_swz(int& bx, int& by) {
    const int gx = gridDim.x;
    const int cpx = (gx * gridDim.y) >> 3;
    const int bid = by * gx + bx;
    const int w = (bid & 7) * cpx + (bid >> 3);
    bx = w % gx; by = w / gx;
}

// ---- dtype detect: if buffer is fp32, even-index u16s are mantissa-low garbage ----
__global__ void detect_kernel(const void* x, int* flag)
{
    __shared__ int bad;
    if (threadIdx.x == 0) bad = 0;
    __syncthreads();
    const u16* p = (const u16*)x;
    int local = 0;
    for (int i = threadIdx.x; i < 2048; i += 256) {
        const float v = bf2f(p[2 * i]);
        if (!(fabsf(v) < 1e4f)) local = 1;
    }
    if (local) atomicOr(&bad, 1);
    __syncthreads();
    if (threadIdx.x == 0) *flag = bad;       // 1 => inputs are fp32
}

// ---- fused weight transpose: 4 jobs in one launch, 64x64 LDS tiles, vectorized ----
__global__ __launch_bounds__(256) void transpose_all_kernel(
    const void* __restrict__ W_in, const void* __restrict__ W_xp,
    const void* __restrict__ W_dt, const void* __restrict__ W_out,
    u16* __restrict__ WtIn, u16* __restrict__ WtXp,
    u16* __restrict__ WtDt, u16* __restrict__ WtOut,
    const int* __restrict__ flagp)
{
    const bool f32 = (*flagp != 0);
    int bid = blockIdx.x;
    const void* src; u16* dst; int K, N, bx, by;
    if (bid < 576)      { src = W_in;  dst = WtIn;  K = 768;  N = 3072; bx = bid % 48; by = bid / 48; }
    else if (bid < 624) { bid -= 576; src = W_xp;  dst = WtXp;  K = 1536; N = 128;  bx = bid % 2;  by = bid / 2; }
    else if (bid < 672) { bid -= 624; src = W_dt;  dst = WtDt;  K = 96;   N = 1536; bx = bid % 24; by = bid / 24; }
    else                { bid -= 672; src = W_out; dst = WtOut; K = 1536; N = 768;  bx = bid % 12; by = bid / 12; }
    __shared__ u16 tile[64][72];
    const int t  = threadIdx.x;
    const int n0 = bx * 64, k0 = by * 64;
    {
        const int r = t >> 2, c = (t & 3) * 16;     // tile-local (k, n)
        const int k = k0 + r;
        if (k < K) {
            if (f32) {
                const float* sp = (const float*)src + (size_t)k * N + n0 + c;
                #pragma unroll
                for (int q = 0; q < 4; ++q) {
                    const float4 v = *(const float4*)(sp + 4 * q);
                    tile[r][c + 4*q + 0] = f2bf(v.x);
                    tile[r][c + 4*q + 1] = f2bf(v.y);
                    tile[r][c + 4*q + 2] = f2bf(v.z);
                    tile[r][c + 4*q + 3] = f2bf(v.w);
                }
            } else {
                const u16* sp = (const u16*)src + (size_t)k * N + n0 + c;
                *(u16x8*)(&tile[r][c])     = *(const u16x8*)(sp);
                *(u16x8*)(&tile[r][c + 8]) = *(const u16x8*)(sp + 8);
            }
        }
    }
    __syncthreads();
    {
        const int nl = t >> 2, kl = (t & 3) * 16;   // tile-local (n, k)
        const int n = n0 + nl;
        if (k0 + kl < K) {                           // groups of 16 fully valid (K%16==0)
            u16x8 t0, t1;
            #pragma unroll
            for (int i = 0; i < 8; ++i) t0[i] = tile[kl + i][nl];
            #pragma unroll
            for (int i = 0; i < 8; ++i) t1[i] = tile[kl + 8 + i][nl];
            u16* dp = dst + (size_t)n * K + k0 + kl;
            *(u16x8*)(dp)     = t0;
            *(u16x8*)(dp + 8) = t1;
        }
    }
}

// ---------------- LayerNorm: x (T,768) -> xn (T,768) bf16 ----------------
__global__ __launch_bounds__(256) void ln_kernel(const void* __restrict__ x,
    const void* __restrict__ g, const void* __restrict__ b, u16* __restrict__ xn,
    const int* __restrict__ flagp)
{
    const bool f32 = (*flagp != 0);
    const int tok = blockIdx.x;
    const int tid = threadIdx.x;
    const size_t base = (size_t)tok * D_MODEL;
    float v[3];
    v[0] = ldx(x, base + tid, f32);
    v[1] = ldx(x, base + tid + 256, f32);
    v[2] = ldx(x, base + tid + 512, f32);
    float s = v[0] + v[1] + v[2];
    float q = v[0]*v[0] + v[1]*v[1] + v[2]*v[2];
    #pragma unroll
    for (int o = 32; o > 0; o >>= 1) {
        s += __shfl_down(s, o, 64);
        q += __shfl_down(q, o, 64);
    }
    __shared__ float ss[4], qq[4];
    if ((tid & 63) == 0) { ss[tid >> 6] = s; qq[tid >> 6] = q; }
    __syncthreads();
    const float S = ss[0] + ss[1] + ss[2] + ss[3];
    const float Q = qq[0] + qq[1] + qq[2] + qq[3];
    const float mu  = S * (1.f / D_MODEL);
    const float var = Q * (1.f / D_MODEL) - mu * mu;
    const float rs  = rsqrtf(var + 1e-5f);
    u16* outr = xn + base;
    #pragma unroll
    for (int i = 0; i < 3; ++i) {
        const int c = tid + i * 256;
        outr[c] = f2bf((v[i] - mu) * rs * ldx(g, c, f32) + ldx(b, c, f32));
    }
}

// ------- MFMA GEMM 64x64 tile, templated BK (32|64), 4 waves, dbuf 1-barrier -------
// BK=64: 8 MFMA + 10 ds_read per barrier (halves latency-exposure events vs BK=32).
// T1 XCD swizzle when gridDim.z==1 (all callers have nwg%8==0).
// EPI 1: softplus(acc+bias[col]). EPI 2: + res[idx] (flex), flex store.
// EPI 3: atomicAdd fp32 (split-K).
template<int EPI, int BK>
__global__ __launch_bounds__(256) void mfma_gemm(
    const u16* __restrict__ A, const u16* __restrict__ Bt,
    u16* __restrict__ C, void* __restrict__ Cout, const void* __restrict__ aux,
    float* __restrict__ Cf, const int* __restrict__ flagp,
    int Kslice, int lda, int ldbt, int ldc)
{
    const bool f32 = (*flagp != 0);
    __shared__ alignas(16) u16 As[2 * 64 * BK];
    __shared__ alignas(16) u16 Bs[2 * 64 * BK];
    const int tid  = threadIdx.x;
    const int wave = tid >> 6, lane = tid & 63;
    const int lrow = lane & 15, quad = lane >> 4;
    int bx = blockIdx.x, by = blockIdx.y;
    if (gridDim.z == 1) xcd_swz(bx, by);
    const int row0 = by * 64, col0 = bx * 64;
    const int k0   = blockIdx.z * Kslice;
    // staging: wave w owns rows [w*16, w*16+16). One gload op = 1024B = 512/BK... rows.
    constexpr int LPR = BK / 8;          // lanes per row (4 @BK32, 8 @BK64)
    constexpr int RPO = 64 / LPR;        // rows per gload op (16 @BK32, 8 @BK64)
    constexpr int NOP = BK / 32;         // gload ops per matrix per wave
    const int srow = lane / LPR;
    const int skk  = (lane % LPR) * 8;
    const int wb   = wave * 16 * BK;     // wave-uniform LDS block (u16 units)
    const u16* gA = A  + (size_t)(row0 + wave * 16 + srow) * lda  + k0 + skk;
    const u16* gB = Bt + (size_t)(col0 + wave * 16 + srow) * ldbt + k0 + skk;
    const int nst = Kslice / BK;
    // prologue: stage tile 0 into buffer 0
    #pragma unroll
    for (int o = 0; o < NOP; ++o) {
        gload16(gA + (size_t)o * RPO * lda,  &As[wb + o * 512]);
        gload16(gB + (size_t)o * RPO * ldbt, &Bs[wb + o * 512]);
    }
    f32x4 acc[4] = {{0.f,0.f,0.f,0.f},{0.f,0.f,0.f,0.f},{0.f,0.f,0.f,0.f},{0.f,0.f,0.f,0.f}};
    int cur = 0;
    for (int t = 0; t < nst; ++t) {
        __syncthreads();                       // drains tile-t loads; joins readers of other buf
        const int boff = cur * (64 * BK);
        if (t + 1 < nst) {
            const int poff = boff ^ (64 * BK);
            const int kt = (t + 1) * BK;
            #pragma unroll
            for (int o = 0; o < NOP; ++o) {
                gload16(gA + kt + (size_t)o * RPO * lda,  &As[poff + wb + o * 512]);
                gload16(gB + kt + (size_t)o * RPO * ldbt, &Bs[poff + wb + o * 512]);
            }
        }
        #pragma unroll
        for (int kk = 0; kk < NOP; ++kk) {
            const bf16x8 af = *(const bf16x8*)(&As[boff + (wave * 16 + lrow) * BK + kk * 32 + quad * 8]);
            #pragma unroll
            for (int q = 0; q < 4; ++q) {
                const bf16x8 bq = *(const bf16x8*)(&Bs[boff + (q * 16 + lrow) * BK + kk * 32 + quad * 8]);
                acc[q] = __builtin_amdgcn_mfma_f32_16x16x32_bf16(af, bq, acc[q], 0, 0, 0);
            }
        }
        cur ^= 1;
    }
    #pragma unroll
    for (int t = 0; t < 4; ++t) {
        #pragma unroll
        for (int r = 0; r < 4; ++r) {
            const int row = row0 + wave * 16 + quad * 4 + r;   // C/D: row=quad*4+reg
            const int col = col0 + t * 16 + lrow;              //      col=lane&15
            const size_t idx = (size_t)row * ldc + col;
            float vv = acc[t][r];
            if (EPI == 1) {
                vv += ldx(aux, col, f32);
                vv = (vv > 20.f) ? vv : log1pf(__expf(vv));
                C[idx] = f2bf(vv);
            } else if (EPI == 2) {
                vv += ldx(aux, idx, f32);
                if (f32) ((float*)Cout)[idx] = vv;
                else     ((u16*)Cout)[idx]   = f2bf(vv);
            } else if (EPI == 3) {
                atomicAdd(&Cf[idx], vv);
            } else {
                C[idx] = f2bf(vv);
            }
        }
    }
}

// ------- MFMA GEMM 128x128 tile, BK=32, 4 waves (2x2), dbuf 1-barrier -------
// EPI 0: bf16 store. EPI 1: softplus(acc + bias[col]) bf16 store.
template<int EPI>
__global__ __launch_bounds__(256) void mfma_gemm128(
    const u16* __restrict__ A, const u16* __restrict__ Bt,
    u16* __restrict__ C, void* __restrict__ Cout, const void* __restrict__ aux,
    const int* __restrict__ flagp,
    int K, int lda, int ldbt, int ldc)
{
    const bool f32 = (*flagp != 0);
    __shared__ alignas(16) u16 As[2 * 128 * 32];
    __shared__ alignas(16) u16 Bs[2 * 128 * 32];
    const int tid  = threadIdx.x;
    const int wave = tid >> 6, lane = tid & 63;
    const int lrow = lane & 15, quad = lane >> 4;
    const int wy = wave >> 1, wx = wave & 1;
    int bx = blockIdx.x, by = blockIdx.y;
    if (gridDim.z == 1) xcd_swz(bx, by);
    const int row0 = by * 128, col0 = bx * 128;
    const int skk = (lane & 3) * 8;
    const int r0 = wave * 16 + (lane >> 2);
    const int r1 = r0 + 64;
    const int wb0 = wave * 512, wb1 = (wave + 4) * 512;
    const u16* gA0 = A  + (size_t)(row0 + r0) * lda  + skk;
    const u16* gA1 = A  + (size_t)(row0 + r1) * lda  + skk;
    const u16* gB0 = Bt + (size_t)(col0 + r0) * ldbt + skk;
    const u16* gB1 = Bt + (size_t)(col0 + r1) * ldbt + skk;
    const int nst = K >> 5;
    gload16(gA0, &As[wb0]);
    gload16(gA1, &As[wb1]);
    gload16(gB0, &Bs[wb0]);
    gload16(gB1, &Bs[wb1]);
    f32x4 acc[4][4];
    #pragma unroll
    for (int i = 0; i < 4; ++i)
        #pragma unroll
        for (int j = 0; j < 4; ++j) acc[i][j] = (f32x4){0.f,0.f,0.f,0.f};
    int cur = 0;
    for (int t = 0; t < nst; ++t) {
        __syncthreads();
        const int boff = cur << 12;            // cur * 128*32
        if (t + 1 < nst) {
            const int poff = boff ^ 4096;
            const int kt = (t + 1) * 32;
            gload16(gA0 + kt, &As[poff + wb0]);
            gload16(gA1 + kt, &As[poff + wb1]);
            gload16(gB0 + kt, &Bs[poff + wb0]);
            gload16(gB1 + kt, &Bs[poff + wb1]);
        }
        bf16x8 af[4], bf_[4];
        #pragma unroll
        for (int i = 0; i < 4; ++i)
            af[i] = *(const bf16x8*)(&As[boff + (wy * 64 + i * 16 + lrow) * 32 + quad * 8]);
        #pragma unroll
        for (int j = 0; j < 4; ++j)
            bf_[j] = *(const bf16x8*)(&Bs[boff + (wx * 64 + j * 16 + lrow) * 32 + quad * 8]);
        #pragma unroll
        for (int i = 0; i < 4; ++i)
            #pragma unroll
            for (int j = 0; j < 4; ++j)
                acc[i][j] = __builtin_amdgcn_mfma_f32_16x16x32_bf16(af[i], bf_[j], acc[i][j], 0, 0, 0);
        cur ^= 1;
    }
    #pragma unroll
    for (int i = 0; i < 4; ++i) {
        #pragma unroll
        for (int j = 0; j < 4; ++j) {
            #pragma unroll
            for (int r = 0; r < 4; ++r) {
                const int row = row0 + wy * 64 + i * 16 + quad * 4 + r;
                const int col = col0 + wx * 64 + j * 16 + lrow;
                const size_t idx = (size_t)row * ldc + col;
                float vv = acc[i][j][r];
                if (EPI == 1) {
                    vv += ldx(aux, col, f32);
                    vv = (vv > 20.f) ? vv : log1pf(__expf(vv));
                    C[idx] = f2bf(vv);
                } else if (EPI == 2) {
                    vv += ldx(aux, idx, f32);
                    if (f32) ((float*)Cout)[idx] = vv;
                    else     ((u16*)Cout)[idx]   = f2bf(vv);
                } else {
                    C[idx] = f2bf(vv);
                }
            }
        }
    }
}

// -------- split-K finalize: xdbl = bf16(xdblF) --------
__global__ __launch_bounds__(256) void convert_kernel(const float* __restrict__ src,
                                                      u16* __restrict__ dst, int n)
{
    const int i = blockIdx.x * 256 + threadIdx.x;
    if (i < n) dst[i] = f2bf(src[i]);
}

// ---- causal depthwise conv (width 4, left-pad 3) + SiLU, 8-wide d vectorized ----
__global__ __launch_bounds__(256) void conv_silu_kernel(
    const u16* __restrict__ uv, const void* __restrict__ cw, const void* __restrict__ cb,
    u16* __restrict__ us, const int* __restrict__ flagp)
{
    const bool f32 = (*flagp != 0);
    const int gid = blockIdx.x * 256 + threadIdx.x;   // TT * 192 threads
    const int nd8 = D_INNER / 8;                      // 192
    const int d8  = gid % nd8;
    const int tok = gid / nd8;
    const int d   = d8 * 8;
    const int l   = tok & (LL - 1);
    float acc[8], w[4][8];
    #pragma unroll
    for (int i = 0; i < 8; ++i) acc[i] = ldx(cb, d + i, f32);
    #pragma unroll
    for (int i = 0; i < 8; ++i) {
        if (f32) {
            const float4 wv = *(const float4*)((const float*)cw + (size_t)(d + i) * 4);
            w[0][i] = wv.x; w[1][i] = wv.y; w[2][i] = wv.z; w[3][i] = wv.w;
        } else {
            const u16* wp = (const u16*)cw + (size_t)(d + i) * 4;
            w[0][i] = bf2f(wp[0]); w[1][i] = bf2f(wp[1]);
            w[2][i] = bf2f(wp[2]); w[3][i] = bf2f(wp[3]);
        }
    }
    #pragma unroll
    for (int j = 0; j < 4; ++j) {
        if (l - 3 + j >= 0) {
            const u16x8 uvv = *(const u16x8*)(&uv[(size_t)(tok - 3 + j) * (2 * D_INNER) + d]);
            #pragma unroll
            for (int i = 0; i < 8; ++i) acc[i] += bf2f(uvv[i]) * w[j][i];
        }
    }
    u16x8 o;
    #pragma unroll
    for (int i = 0; i < 8; ++i) o[i] = f2bf(acc[i] / (1.f + __expf(-acc[i])));
    *(u16x8*)(&us[(size_t)tok * D_INNER + d]) = o;
}

// ----- scan pass 1: per-chunk local scan -> carries (j-major layout, coalesced) -----
// carry layout: [(b*NC+c)][j][d]  -> per-j 4B/lane coalesced stores.
__global__ __launch_bounds__(256) void scan1_kernel(
    const u16* __restrict__ delta, const u16* __restrict__ us,
    const u16* __restrict__ xdbl, const void* __restrict__ log_A,
    float* __restrict__ carryA, float* __restrict__ carryH,
    const int* __restrict__ flagp)
{
    const bool f32 = (*flagp != 0);
    const int d = blockIdx.x * 256 + threadIdx.x;
    const int c = blockIdx.y, b = blockIdx.z;
    float A2[16], h[16];
    #pragma unroll
    for (int j = 0; j < 16; ++j) {
        A2[j] = -__expf(ldx(log_A, d * D_STATE + j, f32)) * LOG2E;
        h[j] = 0.f;
    }
    bool pw = true;
    #pragma unroll
    for (int j = 1; j < 16; ++j)
        pw = pw && (fabsf(A2[j] - (j + 1) * A2[0]) <= 0.02f * (j + 1) * fabsf(A2[0]));
    float sdl = 0.f;
    size_t tok = (size_t)b * LL + c * CL;
    if (pw) {
        #pragma unroll 2
        for (int t = 0; t < CL; ++t, ++tok) {
            const float dl = bf2f(delta[tok * D_INNER + d]);
            const float ul = bf2f(us[tok * D_INNER + d]);
            const uint4 B0 = *(const uint4*)(xdbl + tok * 128 + DT_RANK);
            const uint4 B1 = *(const uint4*)(xdbl + tok * 128 + DT_RANK + 8);
            const float dlul = dl * ul;
            sdl += dl;
            const unsigned int bw[8] = {B0.x,B0.y,B0.z,B0.w,B1.x,B1.y,B1.z,B1.w};
            const float a1 = exp2f(dl * A2[0]);
            float aj = 1.f;
            #pragma unroll
            for (int j = 0; j < 16; ++j) {
                aj *= a1;
                const float Bn = (j & 1) ? bfu_hi(bw[j >> 1]) : bfu_lo(bw[j >> 1]);
                h[j] = aj * h[j] + dlul * Bn;
            }
        }
    } else {
        #pragma unroll 2
        for (int t = 0; t < CL; ++t, ++tok) {
            const float dl = bf2f(delta[tok * D_INNER + d]);
            const float ul = bf2f(us[tok * D_INNER + d]);
            const uint4 B0 = *(const uint4*)(xdbl + tok * 128 + DT_RANK);
            const uint4 B1 = *(const uint4*)(xdbl + tok * 128 + DT_RANK + 8);
            const float dlul = dl * ul;
            sdl += dl;
            const unsigned int bw[8] = {B0.x,B0.y,B0.z,B0.w,B1.x,B1.y,B1.z,B1.w};
            #pragma unroll
            for (int j = 0; j < 16; ++j) {
                const float Bn = (j & 1) ? bfu_hi(bw[j >> 1]) : bfu_lo(bw[j >> 1]);
                h[j] = exp2f(dl * A2[j]) * h[j] + dlul * Bn;
            }
        }
    }
    const size_t ci = ((size_t)b * NC + c) * (D_INNER * D_STATE) + d;
    #pragma unroll
    for (int j = 0; j < 16; ++j) {
        carryA[ci + (size_t)j * D_INNER] = exp2f(A2[j] * sdl);
        carryH[ci + (size_t)j * D_INNER] = h[j];
    }
}

// -------- scan pass 2: exclusive scan over chunk carries (layout-opaque) --------
__global__ __launch_bounds__(256) void scan2_kernel(
    const float* __restrict__ carryA, float* __restrict__ carryH)
{
    const int gid = blockIdx.x * 256 + threadIdx.x;
    const int b   = gid / (D_INNER * D_STATE);
    const int dn  = gid % (D_INNER * D_STATE);
    float hrun = 0.f;
    #pragma unroll
    for (int c = 0; c < NC; ++c) {
        const size_t ci = ((size_t)(b * NC + c) * D_INNER * D_STATE) + dn;
        const float a = carryA[ci], hh = carryH[ci];
        carryH[ci] = hrun;
        hrun = a * hrun + hh;
    }
}

// ------ scan pass 3: re-run chunk seeded with carry (j-major reads); emit gated y ------
__global__ __launch_bounds__(256) void scan3_kernel(
    const u16* __restrict__ delta, const u16* __restrict__ us,
    const u16* __restrict__ xdbl, u16* __restrict__ uv,
    const void* __restrict__ log_A, const void* __restrict__ D_param,
    const float* __restrict__ carryH, const int* __restrict__ flagp)
{
    const bool f32 = (*flagp != 0);
    const int d = blockIdx.x * 256 + threadIdx.x;
    const int c = blockIdx.y, b = blockIdx.z;
    const float Dd = ldx(D_param, d, f32);
    float A2[16], h[16];
    const size_t ci = ((size_t)b * NC + c) * (D_INNER * D_STATE) + d;
    #pragma unroll
    for (int j = 0; j < 16; ++j)
        A2[j] = -__expf(ldx(log_A, d * D_STATE + j, f32)) * LOG2E;
    bool pw = true;
    #pragma unroll
    for (int j = 1; j < 16; ++j)
        pw = pw && (fabsf(A2[j] - (j + 1) * A2[0]) <= 0.02f * (j + 1) * fabsf(A2[0]));
    #pragma unroll
    for (int j = 0; j < 16; ++j)
        h[j] = carryH[ci + (size_t)j * D_INNER];
    size_t tok = (size_t)b * LL + c * CL;
    if (pw) {
        #pragma unroll 2
        for (int t = 0; t < CL; ++t, ++tok) {
            const float dl = bf2f(delta[tok * D_INNER + d]);
            const float ul = bf2f(us[tok * D_INNER + d]);
            const uint4 B0 = *(const uint4*)(xdbl + tok * 128 + DT_RANK);
            const uint4 B1 = *(const uint4*)(xdbl + tok * 128 + DT_RANK + 8);
            const uint4 C0 = *(const uint4*)(xdbl + tok * 128 + DT_RANK + D_STATE);
            const uint4 C1 = *(const uint4*)(xdbl + tok * 128 + DT_RANK + D_STATE + 8);
            const float dlul = dl * ul;
            const unsigned int bw[8] = {B0.x,B0.y,B0.z,B0.w,B1.x,B1.y,B1.z,B1.w};
            const unsigned int cw_[8] = {C0.x,C0.y,C0.z,C0.w,C1.x,C1.y,C1.z,C1.w};
            const float a1 = exp2f(dl * A2[0]);
            float aj = 1.f, p = 0.f;
            #pragma unroll
            for (int j = 0; j < 16; ++j) {
                aj *= a1;
                const float Bn = (j & 1) ? bfu_hi(bw[j >> 1]) : bfu_lo(bw[j >> 1]);
                const float Cn = (j & 1) ? bfu_hi(cw_[j >> 1]) : bfu_lo(cw_[j >> 1]);
                h[j] = aj * h[j] + dlul * Bn;
                p += h[j] * Cn;
            }
            const float vv = bf2f(uv[tok * (2*D_INNER) + D_INNER + d]);
            uv[tok * (2*D_INNER) + d] = f2bf((p + ul * Dd) * (vv / (1.f + __expf(-vv))));
        }
    } else {
        #pragma unroll 2
        for (int t = 0; t < CL; ++t, ++tok) {
            const float dl = bf2f(delta[tok * D_INNER + d]);
            const float ul = bf2f(us[tok * D_INNER + d]);
            const uint4 B0 = *(const uint4*)(xdbl + tok * 128 + DT_RANK);
            const uint4 B1 = *(const uint4*)(xdbl + tok * 128 + DT_RANK + 8);
            const uint4 C0 = *(const uint4*)(xdbl + tok * 128 + DT_RANK + D_STATE);
            const uint4 C1 = *(const uint4*)(xdbl + tok * 128 + DT_RANK + D_STATE + 8);
            const float dlul = dl * ul;
            const unsigned int bw[8] = {B0.x,B0.y,B0.z,B0.w,B1.x,B1.y,B1.z,B1.w};
            const unsigned int cw_[8] = {C0.x,C0.y,C0.z,C0.w,C1.x,C1.y,C1.z,C1.w};
            float p = 0.f;
            #pragma unroll
            for (int j = 0; j < 16; ++j) {
                const float Bn = (j & 1) ? bfu_hi(bw[j >> 1]) : bfu_lo(bw[j >> 1]);
                const float Cn = (j & 1) ? bfu_hi(cw_[j >> 1]) : bfu_lo(cw_[j >> 1]);
                h[j] = exp2f(dl * A2[j]) * h[j] + dlul * Bn;
                p += h[j] * Cn;
            }
            const float vv = bf2f(uv[tok * (2*D_INNER) + D_INNER + d]);
            uv[tok * (2*D_INNER) + d] = f2bf((p + ul * Dd) * (vv / (1.f + __expf(-vv))));
        }
    }
}

extern "C" void kernel_launch(void* const* d_in, const int* in_sizes, int n_in,
                              void* d_out, int out_size, void* d_ws, size_t ws_size,
                              hipStream_t stream)
{
    const void* x      = d_in[0];
    const void* ln_g   = d_in[1];
    const void* ln_b   = d_in[2];
    const void* W_in   = d_in[3];
    const void* conv_w = d_in[4];
    const void* conv_b = d_in[5];
    const void* W_xp   = d_in[6];
    const void* W_dt   = d_in[7];
    const void* b_dt   = d_in[8];
    const void* log_A  = d_in[9];
    const void* D_par  = d_in[10];
    const void* W_out  = d_in[11];

    // workspace (~93 MB): flag | xn | uv | us | xdbl | delta | carryH | carryA |
    //                     WtIn | WtXp | WtDt | WtOut | xdblF
    int* flag  = (int*)d_ws;
    u16* ws    = (u16*)((char*)d_ws + 512);
    u16* xn    = ws;
    u16* uv    = xn + (size_t)TT * D_MODEL;
    u16* us    = uv + (size_t)TT * 2 * D_INNER;
    u16* xdbl  = us + (size_t)TT * D_INNER;
    u16* delta = xdbl + (size_t)TT * 128;
    float* carryH = (float*)(delta + (size_t)TT * D_INNER);
    float* carryA = carryH + (size_t)BB * NC * D_INNER * D_STATE;
    u16* WtIn  = (u16*)(carryA + (size_t)BB * NC * D_INNER * D_STATE);
    u16* WtXp  = WtIn  + (size_t)2 * D_INNER * D_MODEL;
    u16* WtDt  = WtXp  + (size_t)(DT_RANK + 2 * D_STATE) * D_INNER;
    u16* WtOut = WtDt  + (size_t)D_INNER * DT_RANK;
    float* xdblF = (float*)(WtOut + (size_t)D_MODEL * D_INNER);

    detect_kernel<<<1, 256, 0, stream>>>(x, flag);
    transpose_all_kernel<<<960, 256, 0, stream>>>(
        W_in, W_xp, W_dt, W_out, WtIn, WtXp, WtDt, WtOut, flag);
    hipMemsetAsync(xdblF, 0, (size_t)TT * 128 * sizeof(float), stream);

    ln_kernel<<<TT, 256, 0, stream>>>(x, ln_g, ln_b, xn, flag);
    // uv = xn @ W_in  (4096x3072, K=768)  [128x128, 768 blocks, dbuf + swizzle]
    mfma_gemm128<0><<<dim3(2 * D_INNER / 128, TT / 128), 256, 0, stream>>>(
        xn, WtIn, uv, nullptr, nullptr, flag, D_MODEL, D_MODEL, D_MODEL, 2 * D_INNER);
    // us = silu(causal_conv(uv[:, :1536]))  [8-wide vectorized]
    conv_silu_kernel<<<(TT * D_INNER / 8) / 256, 256, 0, stream>>>(uv, conv_w, conv_b, us, flag);
    // xdbl = us @ W_xproj  (4096x128, K=1536)  [64x64 BK=64, split-K x4]
    mfma_gemm<3, 64><<<dim3(2, TT / 64, SKK), 256, 0, stream>>>(
        us, WtXp, nullptr, nullptr, nullptr, xdblF, flag,
        D_INNER / SKK, D_INNER, D_INNER, 128);
    convert_kernel<<<(TT * 128 + 255) / 256, 256, 0, stream>>>(xdblF, xdbl, TT * 128);
    // delta = softplus(xdbl[:, :96] @ W_dt + b_dt)  (4096x1536, K=96)  [BK=32]
    mfma_gemm<1, 32><<<dim3(D_INNER / 64, TT / 64, 1), 256, 0, stream>>>(
        xdbl, WtDt, delta, nullptr, b_dt, nullptr, flag,
        DT_RANK, 128, DT_RANK, D_INNER);
    // chunked selective scan (full-d threads: 768 blocks per pass)
    scan1_kernel<<<dim3(D_INNER / 256, NC, BB), 256, 0, stream>>>(
        delta, us, xdbl, log_A, carryA, carryH, flag);
    scan2_kernel<<<(BB * D_INNER * D_STATE) / 256, 256, 0, stream>>>(carryA, carryH);
    scan3_kernel<<<dim3(D_INNER / 256, NC, BB), 256, 0, stream>>>(
        delta, us, xdbl, uv, log_A, D_par, carryH, flag);
    // out = y @ W_out + x  (4096x768, K=1536)  [64x64 BK=64, 768 blocks, dbuf + swizzle]
    mfma_gemm<2, 64><<<dim3(D_MODEL / 64, TT / 64, 1), 256, 0, stream>>>(
        uv, WtOut, nullptr, d_out, x, nullptr, flag,
        D_INNER, 2 * D_INNER, D_INNER, D_MODEL);
}

// Round 5
// 291.282 us; speedup vs baseline: 1.1739x; 1.0135x over previous
//
#include <hip/hip_runtime.h>

#define D_MODEL 768
#define D_INNER 1536
#define D_STATE 16
#define DT_RANK 96
#define BB 2
#define LL 2048
#define TT (BB*LL)          // 4096 tokens
#define NC 64               // chunks per sequence
#define CL 32               // chunk length
#define SKK 4               // split-K factor for xdbl GEMM
#define LOG2E 1.44269504f

typedef unsigned short u16;
typedef short bf16x8 __attribute__((ext_vector_type(8)));
typedef unsigned short u16x8 __attribute__((ext_vector_type(8)));
typedef float f32x4  __attribute__((ext_vector_type(4)));

__device__ __forceinline__ float bf2f(u16 u) {
    union { unsigned int i; float f; } c; c.i = ((unsigned int)u) << 16; return c.f;
}
__device__ __forceinline__ u16 f2bf(float f) {
    union { float f; unsigned int i; } c; c.f = f;
    unsigned int x = c.i;
    return (u16)((x + 0x7fffu + ((x >> 16) & 1u)) >> 16);   // RNE
}
__device__ __forceinline__ float bfu_lo(unsigned int u) {
    union { unsigned int i; float f; } c; c.i = u << 16; return c.f;
}
__device__ __forceinline__ float bfu_hi(unsigned int u) {
    union { unsigned int i; float f; } c; c.i = u & 0xFFFF0000u; return c.f;
}
__device__ __forceinline__ float ldx(const void* p, size_t i, bool f32) {
    return f32 ? ((const float*)p)[i] : bf2f(((const u16*)p)[i]);
}

// async global->LDS, 16B per lane; LDS dest = wave-uniform base + lane*16
__device__ __forceinline__ void gload16(const u16* g, u16* l) {
    __builtin_amdgcn_global_load_lds(
        (const __attribute__((address_space(1))) unsigned int*)g,
        (__attribute__((address_space(3))) unsigned int*)l, 16, 0, 0);
}

// XCD-aware bijective block swizzle (T1): grids here always have nwg%8==0.
__device__ __forceinline__ void xcd_swz(int& bx, int& by) {
    const int gx = gridDim.x;
    const int cpx = (gx * gridDim.y) >> 3;
    const int bid = by * gx + bx;
    const int w = (bid & 7) * cpx + (bid >> 3);
    bx = w % gx; by = w / gx;
}

// ---- dtype detect: if buffer is fp32, even-index u16s are mantissa-low garbage ----
__global__ void detect_kernel(const void* x, int* flag)
{
    __shared__ int bad;
    if (threadIdx.x == 0) bad = 0;
    __syncthreads();
    const u16* p = (const u16*)x;
    int local = 0;
    for (int i = threadIdx.x; i < 2048; i += 256) {
        const float v = bf2f(p[2 * i]);
        if (!(fabsf(v) < 1e4f)) local = 1;
    }
    if (local) atomicOr(&bad, 1);
    __syncthreads();
    if (threadIdx.x == 0) *flag = bad;       // 1 => inputs are fp32
}

// ---- fused prep: 960 transpose blocks + 4096 LayerNorm blocks in one launch ----
// (both depend only on detect; overlaps two memory-bound phases, saves a dispatch)
__global__ __launch_bounds__(256) void prep_kernel(
    const void* __restrict__ W_in, const void* __restrict__ W_xp,
    const void* __restrict__ W_dt, const void* __restrict__ W_out,
    u16* __restrict__ WtIn, u16* __restrict__ WtXp,
    u16* __restrict__ WtDt, u16* __restrict__ WtOut,
    const void* __restrict__ x, const void* __restrict__ g,
    const void* __restrict__ b, u16* __restrict__ xn,
    const int* __restrict__ flagp)
{
    const bool f32 = (*flagp != 0);
    int bid = blockIdx.x;
    const int t = threadIdx.x;
    if (bid >= 960) {
        // ---------------- LayerNorm branch ----------------
        const int tok = bid - 960;
        const size_t base = (size_t)tok * D_MODEL;
        float v[3];
        v[0] = ldx(x, base + t, f32);
        v[1] = ldx(x, base + t + 256, f32);
        v[2] = ldx(x, base + t + 512, f32);
        float s = v[0] + v[1] + v[2];
        float q = v[0]*v[0] + v[1]*v[1] + v[2]*v[2];
        #pragma unroll
        for (int o = 32; o > 0; o >>= 1) {
            s += __shfl_down(s, o, 64);
            q += __shfl_down(q, o, 64);
        }
        __shared__ float ss[4], qq[4];
        if ((t & 63) == 0) { ss[t >> 6] = s; qq[t >> 6] = q; }
        __syncthreads();
        const float S = ss[0] + ss[1] + ss[2] + ss[3];
        const float Q = qq[0] + qq[1] + qq[2] + qq[3];
        const float mu  = S * (1.f / D_MODEL);
        const float var = Q * (1.f / D_MODEL) - mu * mu;
        const float rs  = rsqrtf(var + 1e-5f);
        u16* outr = xn + base;
        #pragma unroll
        for (int i = 0; i < 3; ++i) {
            const int c = t + i * 256;
            outr[c] = f2bf((v[i] - mu) * rs * ldx(g, c, f32) + ldx(b, c, f32));
        }
        return;
    }
    // ---------------- transpose branch ----------------
    const void* src; u16* dst; int K, N, bx, by;
    if (bid < 576)      { src = W_in;  dst = WtIn;  K = 768;  N = 3072; bx = bid % 48; by = bid / 48; }
    else if (bid < 624) { bid -= 576; src = W_xp;  dst = WtXp;  K = 1536; N = 128;  bx = bid % 2;  by = bid / 2; }
    else if (bid < 672) { bid -= 624; src = W_dt;  dst = WtDt;  K = 96;   N = 1536; bx = bid % 24; by = bid / 24; }
    else                { bid -= 672; src = W_out; dst = WtOut; K = 1536; N = 768;  bx = bid % 12; by = bid / 12; }
    __shared__ u16 tile[64][72];
    const int n0 = bx * 64, k0 = by * 64;
    {
        const int r = t >> 2, c = (t & 3) * 16;     // tile-local (k, n)
        const int k = k0 + r;
        if (k < K) {
            if (f32) {
                const float* sp = (const float*)src + (size_t)k * N + n0 + c;
                #pragma unroll
                for (int q = 0; q < 4; ++q) {
                    const float4 v = *(const float4*)(sp + 4 * q);
                    tile[r][c + 4*q + 0] = f2bf(v.x);
                    tile[r][c + 4*q + 1] = f2bf(v.y);
                    tile[r][c + 4*q + 2] = f2bf(v.z);
                    tile[r][c + 4*q + 3] = f2bf(v.w);
                }
            } else {
                const u16* sp = (const u16*)src + (size_t)k * N + n0 + c;
                *(u16x8*)(&tile[r][c])     = *(const u16x8*)(sp);
                *(u16x8*)(&tile[r][c + 8]) = *(const u16x8*)(sp + 8);
            }
        }
    }
    __syncthreads();
    {
        const int nl = t >> 2, kl = (t & 3) * 16;   // tile-local (n, k)
        const int n = n0 + nl;
        if (k0 + kl < K) {                           // groups of 16 fully valid (K%16==0)
            u16x8 t0, t1;
            #pragma unroll
            for (int i = 0; i < 8; ++i) t0[i] = tile[kl + i][nl];
            #pragma unroll
            for (int i = 0; i < 8; ++i) t1[i] = tile[kl + 8 + i][nl];
            u16* dp = dst + (size_t)n * K + k0 + kl;
            *(u16x8*)(dp)     = t0;
            *(u16x8*)(dp + 8) = t1;
        }
    }
}

// ------- MFMA GEMM 64x64 tile, templated BK (32|64), 4 waves -------
// Depth-3 pipeline: 3 LDS buffers, stage(t+2) -> counted vmcnt -> raw s_barrier ->
// compute(t) -> s_barrier. Tile-t loads get ~2 iterations of latency cover
// (R3/R4 lesson: 2-buffer + __syncthreads drain == only 1 iteration of cover).
// vmcnt BEFORE barrier: each wave certifies its own loads; barrier publishes all.
// EPI 1: softplus(acc+bias[col]). EPI 2: + res[idx] (flex), flex store.
// EPI 3: atomicAdd fp32 (split-K).
template<int EPI, int BK>
__global__ __launch_bounds__(256) void mfma_gemm(
    const u16* __restrict__ A, const u16* __restrict__ Bt,
    u16* __restrict__ C, void* __restrict__ Cout, const void* __restrict__ aux,
    float* __restrict__ Cf, const int* __restrict__ flagp,
    int Kslice, int lda, int ldbt, int ldc)
{
    const bool f32 = (*flagp != 0);
    __shared__ alignas(16) u16 As[3 * 64 * BK];
    __shared__ alignas(16) u16 Bs[3 * 64 * BK];
    const int tid  = threadIdx.x;
    const int wave = tid >> 6, lane = tid & 63;
    const int lrow = lane & 15, quad = lane >> 4;
    int bx = blockIdx.x, by = blockIdx.y;
    if (gridDim.z == 1) xcd_swz(bx, by);
    const int row0 = by * 64, col0 = bx * 64;
    const int k0   = blockIdx.z * Kslice;
    constexpr int LPR = BK / 8;          // lanes per row
    constexpr int RPO = 64 / LPR;        // rows per gload op
    constexpr int NOP = BK / 32;         // gload ops per matrix per wave per batch
    constexpr int V1  = 2 * NOP;         // vmcnt when 1 batch ahead in flight
    constexpr int V2  = 4 * NOP;         // vmcnt when 2 batches ahead in flight
    const int srow = lane / LPR;
    const int skk  = (lane % LPR) * 8;
    const int wb   = wave * 16 * BK;     // wave-uniform LDS block (u16 units)
    const u16* gA = A  + (size_t)(row0 + wave * 16 + srow) * lda  + k0 + skk;
    const u16* gB = Bt + (size_t)(col0 + wave * 16 + srow) * ldbt + k0 + skk;
    const int nst = Kslice / BK;
    constexpr int BUF = 64 * BK;         // u16 per buffer
    // prologue: stage batches 0 (buf0) and 1 (buf1)
    #pragma unroll
    for (int o = 0; o < NOP; ++o) {
        gload16(gA + (size_t)o * RPO * lda,  &As[wb + o * 512]);
        gload16(gB + (size_t)o * RPO * ldbt, &Bs[wb + o * 512]);
    }
    if (nst > 1) {
        #pragma unroll
        for (int o = 0; o < NOP; ++o) {
            gload16(gA + BK + (size_t)o * RPO * lda,  &As[BUF + wb + o * 512]);
            gload16(gB + BK + (size_t)o * RPO * ldbt, &Bs[BUF + wb + o * 512]);
        }
    }
    f32x4 acc[4] = {{0.f,0.f,0.f,0.f},{0.f,0.f,0.f,0.f},{0.f,0.f,0.f,0.f},{0.f,0.f,0.f,0.f}};
    int cur = 0, nxt2 = 2;               // t%3 and (t+2)%3
    for (int t = 0; t < nst; ++t) {
        if (t + 2 < nst) {
            const int kt = (t + 2) * BK;
            const int poff = nxt2 * BUF;
            #pragma unroll
            for (int o = 0; o < NOP; ++o) {
                gload16(gA + kt + (size_t)o * RPO * lda,  &As[poff + wb + o * 512]);
                gload16(gB + kt + (size_t)o * RPO * ldbt, &Bs[poff + wb + o * 512]);
            }
            asm volatile("s_waitcnt vmcnt(%0)" :: "i"(V2) : "memory");
        } else if (t + 1 < nst) {
            asm volatile("s_waitcnt vmcnt(%0)" :: "i"(V1) : "memory");
        } else {
            asm volatile("s_waitcnt vmcnt(0)" ::: "memory");
        }
        __builtin_amdgcn_s_barrier();            // all waves' batch-t loads landed
        asm volatile("" ::: "memory");           // keep ds_reads below the barrier
        const int boff = cur * BUF;
        #pragma unroll
        for (int kk = 0; kk < NOP; ++kk) {
            const bf16x8 af = *(const bf16x8*)(&As[boff + (wave * 16 + lrow) * BK + kk * 32 + quad * 8]);
            #pragma unroll
            for (int q = 0; q < 4; ++q) {
                const bf16x8 bq = *(const bf16x8*)(&Bs[boff + (q * 16 + lrow) * BK + kk * 32 + quad * 8]);
                acc[q] = __builtin_amdgcn_mfma_f32_16x16x32_bf16(af, bq, acc[q], 0, 0, 0);
            }
        }
        __builtin_amdgcn_s_barrier();            // readers done before buf reuse
        asm volatile("" ::: "memory");
        cur = (cur == 2) ? 0 : cur + 1;
        nxt2 = (nxt2 == 2) ? 0 : nxt2 + 1;
    }
    #pragma unroll
    for (int t = 0; t < 4; ++t) {
        #pragma unroll
        for (int r = 0; r < 4; ++r) {
            const int row = row0 + wave * 16 + quad * 4 + r;   // C/D: row=quad*4+reg
            const int col = col0 + t * 16 + lrow;              //      col=lane&15
            const size_t idx = (size_t)row * ldc + col;
            float vv = acc[t][r];
            if (EPI == 1) {
                vv += ldx(aux, col, f32);
                vv = (vv > 20.f) ? vv : log1pf(__expf(vv));
                C[idx] = f2bf(vv);
            } else if (EPI == 2) {
                vv += ldx(aux, idx, f32);
                if (f32) ((float*)Cout)[idx] = vv;
                else     ((u16*)Cout)[idx]   = f2bf(vv);
            } else if (EPI == 3) {
                atomicAdd(&Cf[idx], vv);
            } else {
                C[idx] = f2bf(vv);
            }
        }
    }
}

// ------- MFMA GEMM 128x128 tile, BK=32, 4 waves (2x2), depth-3 pipeline -------
// EPI 0: bf16 store. EPI 1: softplus(acc + bias[col]) bf16 store.
template<int EPI>
__global__ __launch_bounds__(256) void mfma_gemm128(
    const u16* __restrict__ A, const u16* __restrict__ Bt,
    u16* __restrict__ C, void* __restrict__ Cout, const void* __restrict__ aux,
    const int* __restrict__ flagp,
    int K, int lda, int ldbt, int ldc)
{
    const bool f32 = (*flagp != 0);
    __shared__ alignas(16) u16 As[3 * 128 * 32];
    __shared__ alignas(16) u16 Bs[3 * 128 * 32];
    const int tid  = threadIdx.x;
    const int wave = tid >> 6, lane = tid & 63;
    const int lrow = lane & 15, quad = lane >> 4;
    const int wy = wave >> 1, wx = wave & 1;
    int bx = blockIdx.x, by = blockIdx.y;
    if (gridDim.z == 1) xcd_swz(bx, by);
    const int row0 = by * 128, col0 = bx * 128;
    const int skk = (lane & 3) * 8;
    const int r0 = wave * 16 + (lane >> 2);
    const int r1 = r0 + 64;
    const int wb0 = wave * 512, wb1 = (wave + 4) * 512;
    const u16* gA0 = A  + (size_t)(row0 + r0) * lda  + skk;
    const u16* gA1 = A  + (size_t)(row0 + r1) * lda  + skk;
    const u16* gB0 = Bt + (size_t)(col0 + r0) * ldbt + skk;
    const u16* gB1 = Bt + (size_t)(col0 + r1) * ldbt + skk;
    const int nst = K >> 5;
    constexpr int BUF = 128 * 32;
    // prologue: stage batches 0 and 1
    gload16(gA0, &As[wb0]); gload16(gA1, &As[wb1]);
    gload16(gB0, &Bs[wb0]); gload16(gB1, &Bs[wb1]);
    if (nst > 1) {
        gload16(gA0 + 32, &As[BUF + wb0]); gload16(gA1 + 32, &As[BUF + wb1]);
        gload16(gB0 + 32, &Bs[BUF + wb0]); gload16(gB1 + 32, &Bs[BUF + wb1]);
    }
    f32x4 acc[4][4];
    #pragma unroll
    for (int i = 0; i < 4; ++i)
        #pragma unroll
        for (int j = 0; j < 4; ++j) acc[i][j] = (f32x4){0.f,0.f,0.f,0.f};
    int cur = 0, nxt2 = 2;
    for (int t = 0; t < nst; ++t) {
        if (t + 2 < nst) {
            const int kt = (t + 2) * 32;
            const int poff = nxt2 * BUF;
            gload16(gA0 + kt, &As[poff + wb0]); gload16(gA1 + kt, &As[poff + wb1]);
            gload16(gB0 + kt, &Bs[poff + wb0]); gload16(gB1 + kt, &Bs[poff + wb1]);
            asm volatile("s_waitcnt vmcnt(8)" ::: "memory");
        } else if (t + 1 < nst) {
            asm volatile("s_waitcnt vmcnt(4)" ::: "memory");
        } else {
            asm volatile("s_waitcnt vmcnt(0)" ::: "memory");
        }
        __builtin_amdgcn_s_barrier();
        asm volatile("" ::: "memory");
        const int boff = cur * BUF;
        bf16x8 af[4], bf_[4];
        #pragma unroll
        for (int i = 0; i < 4; ++i)
            af[i] = *(const bf16x8*)(&As[boff + (wy * 64 + i * 16 + lrow) * 32 + quad * 8]);
        #pragma unroll
        for (int j = 0; j < 4; ++j)
            bf_[j] = *(const bf16x8*)(&Bs[boff + (wx * 64 + j * 16 + lrow) * 32 + quad * 8]);
        #pragma unroll
        for (int i = 0; i < 4; ++i)
            #pragma unroll
            for (int j = 0; j < 4; ++j)
                acc[i][j] = __builtin_amdgcn_mfma_f32_16x16x32_bf16(af[i], bf_[j], acc[i][j], 0, 0, 0);
        __builtin_amdgcn_s_barrier();
        asm volatile("" ::: "memory");
        cur = (cur == 2) ? 0 : cur + 1;
        nxt2 = (nxt2 == 2) ? 0 : nxt2 + 1;
    }
    #pragma unroll
    for (int i = 0; i < 4; ++i) {
        #pragma unroll
        for (int j = 0; j < 4; ++j) {
            #pragma unroll
            for (int r = 0; r < 4; ++r) {
                const int row = row0 + wy * 64 + i * 16 + quad * 4 + r;
                const int col = col0 + wx * 64 + j * 16 + lrow;
                const size_t idx = (size_t)row * ldc + col;
                float vv = acc[i][j][r];
                if (EPI == 1) {
                    vv += ldx(aux, col, f32);
                    vv = (vv > 20.f) ? vv : log1pf(__expf(vv));
                    C[idx] = f2bf(vv);
                } else if (EPI == 2) {
                    vv += ldx(aux, idx, f32);
                    if (f32) ((float*)Cout)[idx] = vv;
                    else     ((u16*)Cout)[idx]   = f2bf(vv);
                } else {
                    C[idx] = f2bf(vv);
                }
            }
        }
    }
}

// -------- split-K finalize: xdbl = bf16(xdblF) --------
__global__ __launch_bounds__(256) void convert_kernel(const float* __restrict__ src,
                                                      u16* __restrict__ dst, int n)
{
    const int i = blockIdx.x * 256 + threadIdx.x;
    if (i < n) dst[i] = f2bf(src[i]);
}

// ---- causal depthwise conv (width 4, left-pad 3) + SiLU, 8-wide d vectorized ----
__global__ __launch_bounds__(256) void conv_silu_kernel(
    const u16* __restrict__ uv, const void* __restrict__ cw, const void* __restrict__ cb,
    u16* __restrict__ us, const int* __restrict__ flagp)
{
    const bool f32 = (*flagp != 0);
    const int gid = blockIdx.x * 256 + threadIdx.x;   // TT * 192 threads
    const int nd8 = D_INNER / 8;                      // 192
    const int d8  = gid % nd8;
    const int tok = gid / nd8;
    const int d   = d8 * 8;
    const int l   = tok & (LL - 1);
    float acc[8], w[4][8];
    #pragma unroll
    for (int i = 0; i < 8; ++i) acc[i] = ldx(cb, d + i, f32);
    #pragma unroll
    for (int i = 0; i < 8; ++i) {
        if (f32) {
            const float4 wv = *(const float4*)((const float*)cw + (size_t)(d + i) * 4);
            w[0][i] = wv.x; w[1][i] = wv.y; w[2][i] = wv.z; w[3][i] = wv.w;
        } else {
            const u16* wp = (const u16*)cw + (size_t)(d + i) * 4;
            w[0][i] = bf2f(wp[0]); w[1][i] = bf2f(wp[1]);
            w[2][i] = bf2f(wp[2]); w[3][i] = bf2f(wp[3]);
        }
    }
    #pragma unroll
    for (int j = 0; j < 4; ++j) {
        if (l - 3 + j >= 0) {
            const u16x8 uvv = *(const u16x8*)(&uv[(size_t)(tok - 3 + j) * (2 * D_INNER) + d]);
            #pragma unroll
            for (int i = 0; i < 8; ++i) acc[i] += bf2f(uvv[i]) * w[j][i];
        }
    }
    u16x8 o;
    #pragma unroll
    for (int i = 0; i < 8; ++i) o[i] = f2bf(acc[i] / (1.f + __expf(-acc[i])));
    *(u16x8*)(&us[(size_t)tok * D_INNER + d]) = o;
}

// ----- scan pass 1: per-chunk local scan -> carries (j-major carryH, sdl-only decay) -----
// carryH layout: [(b*NC+c)][j][d]; carrySD: [(b*NC+c)][d] (sum of delta; decay recomputed
// in scan2 from log_A -> saves 24 MB of carryA traffic).
__global__ __launch_bounds__(256) void scan1_kernel(
    const u16* __restrict__ delta, const u16* __restrict__ us,
    const u16* __restrict__ xdbl, const void* __restrict__ log_A,
    float* __restrict__ carrySD, float* __restrict__ carryH,
    const int* __restrict__ flagp)
{
    const bool f32 = (*flagp != 0);
    const int d = blockIdx.x * 256 + threadIdx.x;
    const int c = blockIdx.y, b = blockIdx.z;
    float A2[16], h[16];
    #pragma unroll
    for (int j = 0; j < 16; ++j) {
        A2[j] = -__expf(ldx(log_A, d * D_STATE + j, f32)) * LOG2E;
        h[j] = 0.f;
    }
    bool pw = true;
    #pragma unroll
    for (int j = 1; j < 16; ++j)
        pw = pw && (fabsf(A2[j] - (j + 1) * A2[0]) <= 0.02f * (j + 1) * fabsf(A2[0]));
    float sdl = 0.f;
    size_t tok = (size_t)b * LL + c * CL;
    if (pw) {
        #pragma unroll 2
        for (int t = 0; t < CL; ++t, ++tok) {
            const float dl = bf2f(delta[tok * D_INNER + d]);
            const float ul = bf2f(us[tok * D_INNER + d]);
            const uint4 B0 = *(const uint4*)(xdbl + tok * 128 + DT_RANK);
            const uint4 B1 = *(const uint4*)(xdbl + tok * 128 + DT_RANK + 8);
            const float dlul = dl * ul;
            sdl += dl;
            const unsigned int bw[8] = {B0.x,B0.y,B0.z,B0.w,B1.x,B1.y,B1.z,B1.w};
            const float a1 = exp2f(dl * A2[0]);
            float aj = 1.f;
            #pragma unroll
            for (int j = 0; j < 16; ++j) {
                aj *= a1;
                const float Bn = (j & 1) ? bfu_hi(bw[j >> 1]) : bfu_lo(bw[j >> 1]);
                h[j] = aj * h[j] + dlul * Bn;
            }
        }
    } else {
        #pragma unroll 2
        for (int t = 0; t < CL; ++t, ++tok) {
            const float dl = bf2f(delta[tok * D_INNER + d]);
            const float ul = bf2f(us[tok * D_INNER + d]);
            const uint4 B0 = *(const uint4*)(xdbl + tok * 128 + DT_RANK);
            const uint4 B1 = *(const uint4*)(xdbl + tok * 128 + DT_RANK + 8);
            const float dlul = dl * ul;
            sdl += dl;
            const unsigned int bw[8] = {B0.x,B0.y,B0.z,B0.w,B1.x,B1.y,B1.z,B1.w};
            #pragma unroll
            for (int j = 0; j < 16; ++j) {
                const float Bn = (j & 1) ? bfu_hi(bw[j >> 1]) : bfu_lo(bw[j >> 1]);
                h[j] = exp2f(dl * A2[j]) * h[j] + dlul * Bn;
            }
        }
    }
    const size_t cc = (size_t)b * NC + c;
    carrySD[cc * D_INNER + d] = sdl;
    const size_t ci = cc * (D_INNER * D_STATE) + d;
    #pragma unroll
    for (int j = 0; j < 16; ++j)
        carryH[ci + (size_t)j * D_INNER] = h[j];
}

// -------- scan pass 2: exclusive scan over chunk carries; decay from sdl + log_A --------
__global__ __launch_bounds__(256) void scan2_kernel(
    const float* __restrict__ carrySD, float* __restrict__ carryH,
    const void* __restrict__ log_A, const int* __restrict__ flagp)
{
    const bool f32 = (*flagp != 0);
    const int gid = blockIdx.x * 256 + threadIdx.x;
    const int b   = gid / (D_INNER * D_STATE);
    const int dn  = gid % (D_INNER * D_STATE);
    const int j   = dn / D_INNER, d = dn % D_INNER;   // j-major (matches carryH)
    const float A2j = -__expf(ldx(log_A, d * D_STATE + j, f32)) * LOG2E;
    float hrun = 0.f;
    #pragma unroll 4
    for (int c = 0; c < NC; ++c) {
        const size_t cc = (size_t)b * NC + c;
        const float sdl = carrySD[cc * D_INNER + d];
        const size_t ci = cc * (D_INNER * D_STATE) + dn;
        const float hh = carryH[ci];
        carryH[ci] = hrun;
        hrun = exp2f(A2j * sdl) * hrun + hh;
    }
}

// ------ scan pass 3: re-run chunk seeded with carry (j-major reads); emit gated y ------
__global__ __launch_bounds__(256) void scan3_kernel(
    const u16* __restrict__ delta, const u16* __restrict__ us,
    const u16* __restrict__ xdbl, u16* __restrict__ uv,
    const void* __restrict__ log_A, const void* __restrict__ D_param,
    const float* __restrict__ carryH, const int* __restrict__ flagp)
{
    const bool f32 = (*flagp != 0);
    const int d = blockIdx.x * 256 + threadIdx.x;
    const int c = blockIdx.y, b = blockIdx.z;
    const float Dd = ldx(D_param, d, f32);
    float A2[16], h[16];
    const size_t ci = ((size_t)b * NC + c) * (D_INNER * D_STATE) + d;
    #pragma unroll
    for (int j = 0; j < 16; ++j)
        A2[j] = -__expf(ldx(log_A, d * D_STATE + j, f32)) * LOG2E;
    bool pw = true;
    #pragma unroll
    for (int j = 1; j < 16; ++j)
        pw = pw && (fabsf(A2[j] - (j + 1) * A2[0]) <= 0.02f * (j + 1) * fabsf(A2[0]));
    #pragma unroll
    for (int j = 0; j < 16; ++j)
        h[j] = carryH[ci + (size_t)j * D_INNER];
    size_t tok = (size_t)b * LL + c * CL;
    if (pw) {
        #pragma unroll 2
        for (int t = 0; t < CL; ++t, ++tok) {
            const float dl = bf2f(delta[tok * D_INNER + d]);
            const float ul = bf2f(us[tok * D_INNER + d]);
            const uint4 B0 = *(const uint4*)(xdbl + tok * 128 + DT_RANK);
            const uint4 B1 = *(const uint4*)(xdbl + tok * 128 + DT_RANK + 8);
            const uint4 C0 = *(const uint4*)(xdbl + tok * 128 + DT_RANK + D_STATE);
            const uint4 C1 = *(const uint4*)(xdbl + tok * 128 + DT_RANK + D_STATE + 8);
            const float dlul = dl * ul;
            const unsigned int bw[8] = {B0.x,B0.y,B0.z,B0.w,B1.x,B1.y,B1.z,B1.w};
            const unsigned int cw_[8] = {C0.x,C0.y,C0.z,C0.w,C1.x,C1.y,C1.z,C1.w};
            const float a1 = exp2f(dl * A2[0]);
            float aj = 1.f, p = 0.f;
            #pragma unroll
            for (int j = 0; j < 16; ++j) {
                aj *= a1;
                const float Bn = (j & 1) ? bfu_hi(bw[j >> 1]) : bfu_lo(bw[j >> 1]);
                const float Cn = (j & 1) ? bfu_hi(cw_[j >> 1]) : bfu_lo(cw_[j >> 1]);
                h[j] = aj * h[j] + dlul * Bn;
                p += h[j] * Cn;
            }
            const float vv = bf2f(uv[tok * (2*D_INNER) + D_INNER + d]);
            uv[tok * (2*D_INNER) + d] = f2bf((p + ul * Dd) * (vv / (1.f + __expf(-vv))));
        }
    } else {
        #pragma unroll 2
        for (int t = 0; t < CL; ++t, ++tok) {
            const float dl = bf2f(delta[tok * D_INNER + d]);
            const float ul = bf2f(us[tok * D_INNER + d]);
            const uint4 B0 = *(const uint4*)(xdbl + tok * 128 + DT_RANK);
            const uint4 B1 = *(const uint4*)(xdbl + tok * 128 + DT_RANK + 8);
            const uint4 C0 = *(const uint4*)(xdbl + tok * 128 + DT_RANK + D_STATE);
            const uint4 C1 = *(const uint4*)(xdbl + tok * 128 + DT_RANK + D_STATE + 8);
            const float dlul = dl * ul;
            const unsigned int bw[8] = {B0.x,B0.y,B0.z,B0.w,B1.x,B1.y,B1.z,B1.w};
            const unsigned int cw_[8] = {C0.x,C0.y,C0.z,C0.w,C1.x,C1.y,C1.z,C1.w};
            float p = 0.f;
            #pragma unroll
            for (int j = 0; j < 16; ++j) {
                const float Bn = (j & 1) ? bfu_hi(bw[j >> 1]) : bfu_lo(bw[j >> 1]);
                const float Cn = (j & 1) ? bfu_hi(cw_[j >> 1]) : bfu_lo(cw_[j >> 1]);
                h[j] = exp2f(dl * A2[j]) * h[j] + dlul * Bn;
                p += h[j] * Cn;
            }
            const float vv = bf2f(uv[tok * (2*D_INNER) + D_INNER + d]);
            uv[tok * (2*D_INNER) + d] = f2bf((p + ul * Dd) * (vv / (1.f + __expf(-vv))));
        }
    }
}

extern "C" void kernel_launch(void* const* d_in, const int* in_sizes, int n_in,
                              void* d_out, int out_size, void* d_ws, size_t ws_size,
                              hipStream_t stream)
{
    const void* x      = d_in[0];
    const void* ln_g   = d_in[1];
    const void* ln_b   = d_in[2];
    const void* W_in   = d_in[3];
    const void* conv_w = d_in[4];
    const void* conv_b = d_in[5];
    const void* W_xp   = d_in[6];
    const void* W_dt   = d_in[7];
    const void* b_dt   = d_in[8];
    const void* log_A  = d_in[9];
    const void* D_par  = d_in[10];
    const void* W_out  = d_in[11];

    // workspace: flag | xn | uv | us | xdbl | delta | carryH | carrySD |
    //            WtIn | WtXp | WtDt | WtOut | xdblF
    int* flag  = (int*)d_ws;
    u16* ws    = (u16*)((char*)d_ws + 512);
    u16* xn    = ws;
    u16* uv    = xn + (size_t)TT * D_MODEL;
    u16* us    = uv + (size_t)TT * 2 * D_INNER;
    u16* xdbl  = us + (size_t)TT * D_INNER;
    u16* delta = xdbl + (size_t)TT * 128;
    float* carryH  = (float*)(delta + (size_t)TT * D_INNER);
    float* carrySD = carryH + (size_t)BB * NC * D_INNER * D_STATE;
    u16* WtIn  = (u16*)(carrySD + (size_t)BB * NC * D_INNER);
    u16* WtXp  = WtIn  + (size_t)2 * D_INNER * D_MODEL;
    u16* WtDt  = WtXp  + (size_t)(DT_RANK + 2 * D_STATE) * D_INNER;
    u16* WtOut = WtDt  + (size_t)D_INNER * DT_RANK;
    float* xdblF = (float*)(WtOut + (size_t)D_MODEL * D_INNER);

    detect_kernel<<<1, 256, 0, stream>>>(x, flag);
    hipMemsetAsync(xdblF, 0, (size_t)TT * 128 * sizeof(float), stream);
    // fused: weight transposes (960 blocks) + LayerNorm (4096 blocks)
    prep_kernel<<<960 + TT, 256, 0, stream>>>(
        W_in, W_xp, W_dt, W_out, WtIn, WtXp, WtDt, WtOut,
        x, ln_g, ln_b, xn, flag);
    // uv = xn @ W_in  (4096x3072, K=768)  [128x128, 768 blocks, depth-3 + swizzle]
    mfma_gemm128<0><<<dim3(2 * D_INNER / 128, TT / 128), 256, 0, stream>>>(
        xn, WtIn, uv, nullptr, nullptr, flag, D_MODEL, D_MODEL, D_MODEL, 2 * D_INNER);
    // us = silu(causal_conv(uv[:, :1536]))  [8-wide vectorized]
    conv_silu_kernel<<<(TT * D_INNER / 8) / 256, 256, 0, stream>>>(uv, conv_w, conv_b, us, flag);
    // xdbl = us @ W_xproj  (4096x128, K=1536)  [64x64 BK=64, split-K x4, depth-3]
    mfma_gemm<3, 64><<<dim3(2, TT / 64, SKK), 256, 0, stream>>>(
        us, WtXp, nullptr, nullptr, nullptr, xdblF, flag,
        D_INNER / SKK, D_INNER, D_INNER, 128);
    convert_kernel<<<(TT * 128 + 255) / 256, 256, 0, stream>>>(xdblF, xdbl, TT * 128);
    // delta = softplus(xdbl[:, :96] @ W_dt + b_dt)  (4096x1536, K=96)  [BK=32, depth-3]
    mfma_gemm<1, 32><<<dim3(D_INNER / 64, TT / 64, 1), 256, 0, stream>>>(
        xdbl, WtDt, delta, nullptr, b_dt, nullptr, flag,
        DT_RANK, 128, DT_RANK, D_INNER);
    // chunked selective scan (full-d threads: 768 blocks per pass)
    scan1_kernel<<<dim3(D_INNER / 256, NC, BB), 256, 0, stream>>>(
        delta, us, xdbl, log_A, carrySD, carryH, flag);
    scan2_kernel<<<(BB * D_INNER * D_STATE) / 256, 256, 0, stream>>>(
        carrySD, carryH, log_A, flag);
    scan3_kernel<<<dim3(D_INNER / 256, NC, BB), 256, 0, stream>>>(
        delta, us, xdbl, uv, log_A, D_par, carryH, flag);
    // out = y @ W_out + x  (4096x768, K=1536)  [64x64 BK=64, 768 blocks, depth-3 + swizzle]
    mfma_gemm<2, 64><<<dim3(D_MODEL / 64, TT / 64, 1), 256, 0, stream>>>(
        uv, WtOut, nullptr, d_out, x, nullptr, flag,
        D_INNER, 2 * D_INNER, D_INNER, D_MODEL);
}

// Round 6
// 280.257 us; speedup vs baseline: 1.2201x; 1.0393x over previous
//
#include <hip/hip_runtime.h>

#define D_MODEL 768
#define D_INNER 1536
#define D_STATE 16
#define DT_RANK 96
#define BB 2
#define LL 2048
#define TT (BB*LL)          // 4096 tokens
#define NC 64               // chunks per sequence
#define CL 32               // chunk length
#define SKK 4               // split-K factor for xdbl GEMM
#define LOG2E 1.44269504f

typedef unsigned short u16;
typedef short bf16x8 __attribute__((ext_vector_type(8)));
typedef unsigned short u16x8 __attribute__((ext_vector_type(8)));
typedef float f32x4  __attribute__((ext_vector_type(4)));

__device__ __forceinline__ float bf2f(u16 u) {
    union { unsigned int i; float f; } c; c.i = ((unsigned int)u) << 16; return c.f;
}
__device__ __forceinline__ u16 f2bf(float f) {
    union { float f; unsigned int i; } c; c.f = f;
    unsigned int x = c.i;
    return (u16)((x + 0x7fffu + ((x >> 16) & 1u)) >> 16);   // RNE
}
__device__ __forceinline__ float bfu_lo(unsigned int u) {
    union { unsigned int i; float f; } c; c.i = u << 16; return c.f;
}
__device__ __forceinline__ float bfu_hi(unsigned int u) {
    union { unsigned int i; float f; } c; c.i = u & 0xFFFF0000u; return c.f;
}
__device__ __forceinline__ float ldx(const void* p, size_t i, bool f32) {
    return f32 ? ((const float*)p)[i] : bf2f(((const u16*)p)[i]);
}

// async global->LDS, 16B per lane; LDS dest = wave-uniform base + lane*16
__device__ __forceinline__ void gload16(const u16* g, u16* l) {
    __builtin_amdgcn_global_load_lds(
        (const __attribute__((address_space(1))) unsigned int*)g,
        (__attribute__((address_space(3))) unsigned int*)l, 16, 0, 0);
}

// XCD-aware bijective block swizzle (T1): grids here always have nwg%8==0.
__device__ __forceinline__ void xcd_swz(int& bx, int& by) {
    const int gx = gridDim.x;
    const int cpx = (gx * gridDim.y) >> 3;
    const int bid = by * gx + bx;
    const int w = (bid & 7) * cpx + (bid >> 3);
    bx = w % gx; by = w / gx;
}

// ---- fused prep: 960 transpose blocks + 4096 LayerNorm blocks; computes dtype
// flag locally per-block (block 0 publishes for downstream kernels). ----
__global__ __launch_bounds__(256) void prep_kernel(
    const void* __restrict__ W_in, const void* __restrict__ W_xp,
    const void* __restrict__ W_dt, const void* __restrict__ W_out,
    u16* __restrict__ WtIn, u16* __restrict__ WtXp,
    u16* __restrict__ WtDt, u16* __restrict__ WtOut,
    const void* __restrict__ x, const void* __restrict__ g,
    const void* __restrict__ b, u16* __restrict__ xn,
    int* __restrict__ flagw)
{
    const int t = threadIdx.x;
    // ---- local dtype detect: fp32 buffers have garbage at even u16 indices ----
    __shared__ int sbad;
    if (t == 0) sbad = 0;
    __syncthreads();
    {
        const u16* px = (const u16*)x;
        int bad = 0;
        for (int i = t; i < 2048; i += 256)
            if (!(fabsf(bf2f(px[2 * i])) < 1e4f)) bad = 1;
        if (bad) atomicOr(&sbad, 1);
    }
    __syncthreads();
    const bool f32 = (sbad != 0);
    int bid = blockIdx.x;
    if (bid == 0 && t == 0) *flagw = sbad;
    if (bid >= 960) {
        // ---------------- LayerNorm branch ----------------
        const int tok = bid - 960;
        const size_t base = (size_t)tok * D_MODEL;
        float v[3];
        v[0] = ldx(x, base + t, f32);
        v[1] = ldx(x, base + t + 256, f32);
        v[2] = ldx(x, base + t + 512, f32);
        float s = v[0] + v[1] + v[2];
        float q = v[0]*v[0] + v[1]*v[1] + v[2]*v[2];
        #pragma unroll
        for (int o = 32; o > 0; o >>= 1) {
            s += __shfl_down(s, o, 64);
            q += __shfl_down(q, o, 64);
        }
        __shared__ float ss[4], qq[4];
        if ((t & 63) == 0) { ss[t >> 6] = s; qq[t >> 6] = q; }
        __syncthreads();
        const float S = ss[0] + ss[1] + ss[2] + ss[3];
        const float Q = qq[0] + qq[1] + qq[2] + qq[3];
        const float mu  = S * (1.f / D_MODEL);
        const float var = Q * (1.f / D_MODEL) - mu * mu;
        const float rs  = rsqrtf(var + 1e-5f);
        u16* outr = xn + base;
        #pragma unroll
        for (int i = 0; i < 3; ++i) {
            const int c = t + i * 256;
            outr[c] = f2bf((v[i] - mu) * rs * ldx(g, c, f32) + ldx(b, c, f32));
        }
        return;
    }
    // ---------------- transpose branch ----------------
    const void* src; u16* dst; int K, N, bx, by;
    if (bid < 576)      { src = W_in;  dst = WtIn;  K = 768;  N = 3072; bx = bid % 48; by = bid / 48; }
    else if (bid < 624) { bid -= 576; src = W_xp;  dst = WtXp;  K = 1536; N = 128;  bx = bid % 2;  by = bid / 2; }
    else if (bid < 672) { bid -= 624; src = W_dt;  dst = WtDt;  K = 96;   N = 1536; bx = bid % 24; by = bid / 24; }
    else                { bid -= 672; src = W_out; dst = WtOut; K = 1536; N = 768;  bx = bid % 12; by = bid / 12; }
    __shared__ u16 tile[64][72];
    const int n0 = bx * 64, k0 = by * 64;
    {
        const int r = t >> 2, c = (t & 3) * 16;     // tile-local (k, n)
        const int k = k0 + r;
        if (k < K) {
            if (f32) {
                const float* sp = (const float*)src + (size_t)k * N + n0 + c;
                #pragma unroll
                for (int q = 0; q < 4; ++q) {
                    const float4 v = *(const float4*)(sp + 4 * q);
                    tile[r][c + 4*q + 0] = f2bf(v.x);
                    tile[r][c + 4*q + 1] = f2bf(v.y);
                    tile[r][c + 4*q + 2] = f2bf(v.z);
                    tile[r][c + 4*q + 3] = f2bf(v.w);
                }
            } else {
                const u16* sp = (const u16*)src + (size_t)k * N + n0 + c;
                *(u16x8*)(&tile[r][c])     = *(const u16x8*)(sp);
                *(u16x8*)(&tile[r][c + 8]) = *(const u16x8*)(sp + 8);
            }
        }
    }
    __syncthreads();
    {
        const int nl = t >> 2, kl = (t & 3) * 16;   // tile-local (n, k)
        const int n = n0 + nl;
        if (k0 + kl < K) {                           // groups of 16 fully valid (K%16==0)
            u16x8 t0, t1;
            #pragma unroll
            for (int i = 0; i < 8; ++i) t0[i] = tile[kl + i][nl];
            #pragma unroll
            for (int i = 0; i < 8; ++i) t1[i] = tile[kl + 8 + i][nl];
            u16* dp = dst + (size_t)n * K + k0 + kl;
            *(u16x8*)(dp)     = t0;
            *(u16x8*)(dp + 8) = t1;
        }
    }
}

// ------- MFMA GEMM 64x64 tile, templated BK (32|64), 4 waves, depth-3 pipeline -------
// T2 LDS XOR-swizzle (rule #21: linear gload_lds dest + permuted GLOBAL source +
// XOR'd read). BK=64 un-swizzled was a 16-way bank conflict (row stride 128B = 32
// banks); swizzled = 8 slots x 2-way = free. BK=32: 8-way -> 4-way.
// EPI 1: softplus(acc+bias[col]). EPI 2: + res[idx] (flex), flex store.
// EPI 3: per-slice fp32 store (split-K, no atomics).
template<int EPI, int BK>
__global__ __launch_bounds__(256) void mfma_gemm(
    const u16* __restrict__ A, const u16* __restrict__ Bt,
    u16* __restrict__ C, void* __restrict__ Cout, const void* __restrict__ aux,
    float* __restrict__ Cf, const int* __restrict__ flagp,
    int Kslice, int lda, int ldbt, int ldc)
{
    const bool f32 = (*flagp != 0);
    __shared__ alignas(16) u16 As[3 * 64 * BK];
    __shared__ alignas(16) u16 Bs[3 * 64 * BK];
    const int tid  = threadIdx.x;
    const int wave = tid >> 6, lane = tid & 63;
    const int lrow = lane & 15, quad = lane >> 4;
    int bx = blockIdx.x, by = blockIdx.y;
    if (gridDim.z == 1) xcd_swz(bx, by);
    const int row0 = by * 64, col0 = bx * 64;
    const int k0   = blockIdx.z * Kslice;
    constexpr int LPR = BK / 8;          // lanes per row (16B slots per row)
    constexpr int PM  = LPR - 1;         // swizzle mask
    constexpr int RPO = 64 / LPR;        // rows per gload op
    constexpr int NOP = BK / 32;         // gload ops per matrix per wave per batch
    constexpr int V1  = 2 * NOP;         // vmcnt: 1 batch ahead in flight
    constexpr int V2  = 4 * NOP;         // vmcnt: 2 batches ahead in flight
    const int srow = lane / LPR;                     // row within gload op
    const int pc   = (lane % LPR) ^ (srow & PM);     // swizzled 16B slot
    const int skk  = pc * 8;
    const int wb   = wave * 16 * BK;     // wave-uniform LDS block (u16 units)
    const u16* gA = A  + (size_t)(row0 + wave * 16 + srow) * lda  + k0 + skk;
    const u16* gB = Bt + (size_t)(col0 + wave * 16 + srow) * ldbt + k0 + skk;
    const int nst = Kslice / BK;
    constexpr int BUF = 64 * BK;         // u16 per buffer
    // prologue: stage batches 0 (buf0) and 1 (buf1)
    #pragma unroll
    for (int o = 0; o < NOP; ++o) {
        gload16(gA + (size_t)o * RPO * lda,  &As[wb + o * 512]);
        gload16(gB + (size_t)o * RPO * ldbt, &Bs[wb + o * 512]);
    }
    if (nst > 1) {
        #pragma unroll
        for (int o = 0; o < NOP; ++o) {
            gload16(gA + BK + (size_t)o * RPO * lda,  &As[BUF + wb + o * 512]);
            gload16(gB + BK + (size_t)o * RPO * ldbt, &Bs[BUF + wb + o * 512]);
        }
    }
    f32x4 acc[4] = {{0.f,0.f,0.f,0.f},{0.f,0.f,0.f,0.f},{0.f,0.f,0.f,0.f},{0.f,0.f,0.f,0.f}};
    const int sw = (lrow & PM) << 3;     // read-side XOR (u16 units)
    int cur = 0, nxt2 = 2;               // t%3 and (t+2)%3
    for (int t = 0; t < nst; ++t) {
        if (t + 2 < nst) {
            const int kt = (t + 2) * BK;
            const int poff = nxt2 * BUF;
            #pragma unroll
            for (int o = 0; o < NOP; ++o) {
                gload16(gA + kt + (size_t)o * RPO * lda,  &As[poff + wb + o * 512]);
                gload16(gB + kt + (size_t)o * RPO * ldbt, &Bs[poff + wb + o * 512]);
            }
            asm volatile("s_waitcnt vmcnt(%0)" :: "i"(V2) : "memory");
        } else if (t + 1 < nst) {
            asm volatile("s_waitcnt vmcnt(%0)" :: "i"(V1) : "memory");
        } else {
            asm volatile("s_waitcnt vmcnt(0)" ::: "memory");
        }
        __builtin_amdgcn_s_barrier();            // all waves' batch-t loads landed
        asm volatile("" ::: "memory");
        const int boff = cur * BUF;
        #pragma unroll
        for (int kk = 0; kk < NOP; ++kk) {
            const bf16x8 af = *(const bf16x8*)(
                &As[boff + (wave * 16 + lrow) * BK + ((kk * 32 + quad * 8) ^ sw)]);
            #pragma unroll
            for (int q = 0; q < 4; ++q) {
                const bf16x8 bq = *(const bf16x8*)(
                    &Bs[boff + (q * 16 + lrow) * BK + ((kk * 32 + quad * 8) ^ sw)]);
                acc[q] = __builtin_amdgcn_mfma_f32_16x16x32_bf16(af, bq, acc[q], 0, 0, 0);
            }
        }
        __builtin_amdgcn_s_barrier();            // readers done before buf reuse
        asm volatile("" ::: "memory");
        cur = (cur == 2) ? 0 : cur + 1;
        nxt2 = (nxt2 == 2) ? 0 : nxt2 + 1;
    }
    #pragma unroll
    for (int t = 0; t < 4; ++t) {
        #pragma unroll
        for (int r = 0; r < 4; ++r) {
            const int row = row0 + wave * 16 + quad * 4 + r;   // C/D: row=quad*4+reg
            const int col = col0 + t * 16 + lrow;              //      col=lane&15
            const size_t idx = (size_t)row * ldc + col;
            float vv = acc[t][r];
            if (EPI == 1) {
                vv += ldx(aux, col, f32);
                vv = (vv > 20.f) ? vv : log1pf(__expf(vv));
                C[idx] = f2bf(vv);
            } else if (EPI == 2) {
                vv += ldx(aux, idx, f32);
                if (f32) ((float*)Cout)[idx] = vv;
                else     ((u16*)Cout)[idx]   = f2bf(vv);
            } else if (EPI == 3) {
                Cf[(size_t)blockIdx.z * (TT * 128) + idx] = vv;   // per-slice store
            } else {
                C[idx] = f2bf(vv);
            }
        }
    }
}

// ------- MFMA GEMM 128x128 tile, BK=32, 4 waves (2x2), depth-3 + T2 swizzle -------
// EPI 0: bf16 store. EPI 1: softplus(acc + bias[col]) bf16 store.
template<int EPI>
__global__ __launch_bounds__(256) void mfma_gemm128(
    const u16* __restrict__ A, const u16* __restrict__ Bt,
    u16* __restrict__ C, void* __restrict__ Cout, const void* __restrict__ aux,
    const int* __restrict__ flagp,
    int K, int lda, int ldbt, int ldc)
{
    const bool f32 = (*flagp != 0);
    __shared__ alignas(16) u16 As[3 * 128 * 32];
    __shared__ alignas(16) u16 Bs[3 * 128 * 32];
    const int tid  = threadIdx.x;
    const int wave = tid >> 6, lane = tid & 63;
    const int lrow = lane & 15, quad = lane >> 4;
    const int wy = wave >> 1, wx = wave & 1;
    int bx = blockIdx.x, by = blockIdx.y;
    if (gridDim.z == 1) xcd_swz(bx, by);
    const int row0 = by * 128, col0 = bx * 128;
    const int srw = lane >> 2;                        // row within gload op
    const int pc  = (lane & 3) ^ (srw & 3);           // swizzled 16B slot
    const int skk = pc * 8;
    const int r0 = wave * 16 + srw;
    const int r1 = r0 + 64;
    const int wb0 = wave * 512, wb1 = (wave + 4) * 512;
    const u16* gA0 = A  + (size_t)(row0 + r0) * lda  + skk;
    const u16* gA1 = A  + (size_t)(row0 + r1) * lda  + skk;
    const u16* gB0 = Bt + (size_t)(col0 + r0) * ldbt + skk;
    const u16* gB1 = Bt + (size_t)(col0 + r1) * ldbt + skk;
    const int nst = K >> 5;
    constexpr int BUF = 128 * 32;
    gload16(gA0, &As[wb0]); gload16(gA1, &As[wb1]);
    gload16(gB0, &Bs[wb0]); gload16(gB1, &Bs[wb1]);
    if (nst > 1) {
        gload16(gA0 + 32, &As[BUF + wb0]); gload16(gA1 + 32, &As[BUF + wb1]);
        gload16(gB0 + 32, &Bs[BUF + wb0]); gload16(gB1 + 32, &Bs[BUF + wb1]);
    }
    f32x4 acc[4][4];
    #pragma unroll
    for (int i = 0; i < 4; ++i)
        #pragma unroll
        for (int j = 0; j < 4; ++j) acc[i][j] = (f32x4){0.f,0.f,0.f,0.f};
    const int sw = (lrow & 3) << 3;      // read-side XOR (u16 units)
    int cur = 0, nxt2 = 2;
    for (int t = 0; t < nst; ++t) {
        if (t + 2 < nst) {
            const int kt = (t + 2) * 32;
            const int poff = nxt2 * BUF;
            gload16(gA0 + kt, &As[poff + wb0]); gload16(gA1 + kt, &As[poff + wb1]);
            gload16(gB0 + kt, &Bs[poff + wb0]); gload16(gB1 + kt, &Bs[poff + wb1]);
            asm volatile("s_waitcnt vmcnt(8)" ::: "memory");
        } else if (t + 1 < nst) {
            asm volatile("s_waitcnt vmcnt(4)" ::: "memory");
        } else {
            asm volatile("s_waitcnt vmcnt(0)" ::: "memory");
        }
        __builtin_amdgcn_s_barrier();
        asm volatile("" ::: "memory");
        const int boff = cur * BUF;
        bf16x8 af[4], bf_[4];
        #pragma unroll
        for (int i = 0; i < 4; ++i)
            af[i] = *(const bf16x8*)(
                &As[boff + (wy * 64 + i * 16 + lrow) * 32 + ((quad * 8) ^ sw)]);
        #pragma unroll
        for (int j = 0; j < 4; ++j)
            bf_[j] = *(const bf16x8*)(
                &Bs[boff + (wx * 64 + j * 16 + lrow) * 32 + ((quad * 8) ^ sw)]);
        #pragma unroll
        for (int i = 0; i < 4; ++i)
            #pragma unroll
            for (int j = 0; j < 4; ++j)
                acc[i][j] = __builtin_amdgcn_mfma_f32_16x16x32_bf16(af[i], bf_[j], acc[i][j], 0, 0, 0);
        __builtin_amdgcn_s_barrier();
        asm volatile("" ::: "memory");
        cur = (cur == 2) ? 0 : cur + 1;
        nxt2 = (nxt2 == 2) ? 0 : nxt2 + 1;
    }
    #pragma unroll
    for (int i = 0; i < 4; ++i) {
        #pragma unroll
        for (int j = 0; j < 4; ++j) {
            #pragma unroll
            for (int r = 0; r < 4; ++r) {
                const int row = row0 + wy * 64 + i * 16 + quad * 4 + r;
                const int col = col0 + wx * 64 + j * 16 + lrow;
                const size_t idx = (size_t)row * ldc + col;
                float vv = acc[i][j][r];
                if (EPI == 1) {
                    vv += ldx(aux, col, f32);
                    vv = (vv > 20.f) ? vv : log1pf(__expf(vv));
                    C[idx] = f2bf(vv);
                } else if (EPI == 2) {
                    vv += ldx(aux, idx, f32);
                    if (f32) ((float*)Cout)[idx] = vv;
                    else     ((u16*)Cout)[idx]   = f2bf(vv);
                } else {
                    C[idx] = f2bf(vv);
                }
            }
        }
    }
}

// -------- split-K finalize: xdbl = bf16(sum of 4 slices) --------
__global__ __launch_bounds__(256) void convert_kernel(const float* __restrict__ src,
                                                      u16* __restrict__ dst, int n)
{
    const int i = blockIdx.x * 256 + threadIdx.x;
    if (i < n)
        dst[i] = f2bf(src[i] + src[i + TT*128] + src[i + 2*TT*128] + src[i + 3*TT*128]);
}

// ---- causal depthwise conv (width 4, left-pad 3) + SiLU, 8-wide d vectorized ----
__global__ __launch_bounds__(256) void conv_silu_kernel(
    const u16* __restrict__ uv, const void* __restrict__ cw, const void* __restrict__ cb,
    u16* __restrict__ us, const int* __restrict__ flagp)
{
    const bool f32 = (*flagp != 0);
    const int gid = blockIdx.x * 256 + threadIdx.x;   // TT * 192 threads
    const int nd8 = D_INNER / 8;                      // 192
    const int d8  = gid % nd8;
    const int tok = gid / nd8;
    const int d   = d8 * 8;
    const int l   = tok & (LL - 1);
    float acc[8], w[4][8];
    #pragma unroll
    for (int i = 0; i < 8; ++i) acc[i] = ldx(cb, d + i, f32);
    #pragma unroll
    for (int i = 0; i < 8; ++i) {
        if (f32) {
            const float4 wv = *(const float4*)((const float*)cw + (size_t)(d + i) * 4);
            w[0][i] = wv.x; w[1][i] = wv.y; w[2][i] = wv.z; w[3][i] = wv.w;
        } else {
            const u16* wp = (const u16*)cw + (size_t)(d + i) * 4;
            w[0][i] = bf2f(wp[0]); w[1][i] = bf2f(wp[1]);
            w[2][i] = bf2f(wp[2]); w[3][i] = bf2f(wp[3]);
        }
    }
    #pragma unroll
    for (int j = 0; j < 4; ++j) {
        if (l - 3 + j >= 0) {
            const u16x8 uvv = *(const u16x8*)(&uv[(size_t)(tok - 3 + j) * (2 * D_INNER) + d]);
            #pragma unroll
            for (int i = 0; i < 8; ++i) acc[i] += bf2f(uvv[i]) * w[j][i];
        }
    }
    u16x8 o;
    #pragma unroll
    for (int i = 0; i < 8; ++i) o[i] = f2bf(acc[i] / (1.f + __expf(-acc[i])));
    *(u16x8*)(&us[(size_t)tok * D_INNER + d]) = o;
}

// ----- scan pass 1: per-chunk local scan -> carries (j-major carryH, sdl-only decay) -----
__global__ __launch_bounds__(256) void scan1_kernel(
    const u16* __restrict__ delta, const u16* __restrict__ us,
    const u16* __restrict__ xdbl, const void* __restrict__ log_A,
    float* __restrict__ carrySD, float* __restrict__ carryH,
    const int* __restrict__ flagp)
{
    const bool f32 = (*flagp != 0);
    const int d = blockIdx.x * 256 + threadIdx.x;
    const int c = blockIdx.y, b = blockIdx.z;
    float A2[16], h[16];
    #pragma unroll
    for (int j = 0; j < 16; ++j) {
        A2[j] = -__expf(ldx(log_A, d * D_STATE + j, f32)) * LOG2E;
        h[j] = 0.f;
    }
    bool pw = true;
    #pragma unroll
    for (int j = 1; j < 16; ++j)
        pw = pw && (fabsf(A2[j] - (j + 1) * A2[0]) <= 0.02f * (j + 1) * fabsf(A2[0]));
    float sdl = 0.f;
    size_t tok = (size_t)b * LL + c * CL;
    if (pw) {
        #pragma unroll 2
        for (int t = 0; t < CL; ++t, ++tok) {
            const float dl = bf2f(delta[tok * D_INNER + d]);
            const float ul = bf2f(us[tok * D_INNER + d]);
            const uint4 B0 = *(const uint4*)(xdbl + tok * 128 + DT_RANK);
            const uint4 B1 = *(const uint4*)(xdbl + tok * 128 + DT_RANK + 8);
            const float dlul = dl * ul;
            sdl += dl;
            const unsigned int bw[8] = {B0.x,B0.y,B0.z,B0.w,B1.x,B1.y,B1.z,B1.w};
            const float a1 = exp2f(dl * A2[0]);
            float aj = 1.f;
            #pragma unroll
            for (int j = 0; j < 16; ++j) {
                aj *= a1;
                const float Bn = (j & 1) ? bfu_hi(bw[j >> 1]) : bfu_lo(bw[j >> 1]);
                h[j] = aj * h[j] + dlul * Bn;
            }
        }
    } else {
        #pragma unroll 2
        for (int t = 0; t < CL; ++t, ++tok) {
            const float dl = bf2f(delta[tok * D_INNER + d]);
            const float ul = bf2f(us[tok * D_INNER + d]);
            const uint4 B0 = *(const uint4*)(xdbl + tok * 128 + DT_RANK);
            const uint4 B1 = *(const uint4*)(xdbl + tok * 128 + DT_RANK + 8);
            const float dlul = dl * ul;
            sdl += dl;
            const unsigned int bw[8] = {B0.x,B0.y,B0.z,B0.w,B1.x,B1.y,B1.z,B1.w};
            #pragma unroll
            for (int j = 0; j < 16; ++j) {
                const float Bn = (j & 1) ? bfu_hi(bw[j >> 1]) : bfu_lo(bw[j >> 1]);
                h[j] = exp2f(dl * A2[j]) * h[j] + dlul * Bn;
            }
        }
    }
    const size_t cc = (size_t)b * NC + c;
    carrySD[cc * D_INNER + d] = sdl;
    const size_t ci = cc * (D_INNER * D_STATE) + d;
    #pragma unroll
    for (int j = 0; j < 16; ++j)
        carryH[ci + (size_t)j * D_INNER] = h[j];
}

// -------- scan pass 2: exclusive scan over chunk carries; decay from sdl + log_A --------
__global__ __launch_bounds__(256) void scan2_kernel(
    const float* __restrict__ carrySD, float* __restrict__ carryH,
    const void* __restrict__ log_A, const int* __restrict__ flagp)
{
    const bool f32 = (*flagp != 0);
    const int gid = blockIdx.x * 256 + threadIdx.x;
    const int b   = gid / (D_INNER * D_STATE);
    const int dn  = gid % (D_INNER * D_STATE);
    const int j   = dn / D_INNER, d = dn % D_INNER;   // j-major (matches carryH)
    const float A2j = -__expf(ldx(log_A, d * D_STATE + j, f32)) * LOG2E;
    float hrun = 0.f;
    #pragma unroll 4
    for (int c = 0; c < NC; ++c) {
        const size_t cc = (size_t)b * NC + c;
        const float sdl = carrySD[cc * D_INNER + d];
        const size_t ci = cc * (D_INNER * D_STATE) + dn;
        const float hh = carryH[ci];
        carryH[ci] = hrun;
        hrun = exp2f(A2j * sdl) * hrun + hh;
    }
}

// ------ scan pass 3: re-run chunk seeded with carry (j-major reads); emit gated y ------
__global__ __launch_bounds__(256) void scan3_kernel(
    const u16* __restrict__ delta, const u16* __restrict__ us,
    const u16* __restrict__ xdbl, u16* __restrict__ uv,
    const void* __restrict__ log_A, const void* __restrict__ D_param,
    const float* __restrict__ carryH, const int* __restrict__ flagp)
{
    const bool f32 = (*flagp != 0);
    const int d = blockIdx.x * 256 + threadIdx.x;
    const int c = blockIdx.y, b = blockIdx.z;
    const float Dd = ldx(D_param, d, f32);
    float A2[16], h[16];
    const size_t ci = ((size_t)b * NC + c) * (D_INNER * D_STATE) + d;
    #pragma unroll
    for (int j = 0; j < 16; ++j)
        A2[j] = -__expf(ldx(log_A, d * D_STATE + j, f32)) * LOG2E;
    bool pw = true;
    #pragma unroll
    for (int j = 1; j < 16; ++j)
        pw = pw && (fabsf(A2[j] - (j + 1) * A2[0]) <= 0.02f * (j + 1) * fabsf(A2[0]));
    #pragma unroll
    for (int j = 0; j < 16; ++j)
        h[j] = carryH[ci + (size_t)j * D_INNER];
    size_t tok = (size_t)b * LL + c * CL;
    if (pw) {
        #pragma unroll 2
        for (int t = 0; t < CL; ++t, ++tok) {
            const float dl = bf2f(delta[tok * D_INNER + d]);
            const float ul = bf2f(us[tok * D_INNER + d]);
            const uint4 B0 = *(const uint4*)(xdbl + tok * 128 + DT_RANK);
            const uint4 B1 = *(const uint4*)(xdbl + tok * 128 + DT_RANK + 8);
            const uint4 C0 = *(const uint4*)(xdbl + tok * 128 + DT_RANK + D_STATE);
            const uint4 C1 = *(const uint4*)(xdbl + tok * 128 + DT_RANK + D_STATE + 8);
            const float dlul = dl * ul;
            const unsigned int bw[8] = {B0.x,B0.y,B0.z,B0.w,B1.x,B1.y,B1.z,B1.w};
            const unsigned int cw_[8] = {C0.x,C0.y,C0.z,C0.w,C1.x,C1.y,C1.z,C1.w};
            const float a1 = exp2f(dl * A2[0]);
            float aj = 1.f, p = 0.f;
            #pragma unroll
            for (int j = 0; j < 16; ++j) {
                aj *= a1;
                const float Bn = (j & 1) ? bfu_hi(bw[j >> 1]) : bfu_lo(bw[j >> 1]);
                const float Cn = (j & 1) ? bfu_hi(cw_[j >> 1]) : bfu_lo(cw_[j >> 1]);
                h[j] = aj * h[j] + dlul * Bn;
                p += h[j] * Cn;
            }
            const float vv = bf2f(uv[tok * (2*D_INNER) + D_INNER + d]);
            uv[tok * (2*D_INNER) + d] = f2bf((p + ul * Dd) * (vv / (1.f + __expf(-vv))));
        }
    } else {
        #pragma unroll 2
        for (int t = 0; t < CL; ++t, ++tok) {
            const float dl = bf2f(delta[tok * D_INNER + d]);
            const float ul = bf2f(us[tok * D_INNER + d]);
            const uint4 B0 = *(const uint4*)(xdbl + tok * 128 + DT_RANK);
            const uint4 B1 = *(const uint4*)(xdbl + tok * 128 + DT_RANK + 8);
            const uint4 C0 = *(const uint4*)(xdbl + tok * 128 + DT_RANK + D_STATE);
            const uint4 C1 = *(const uint4*)(xdbl + tok * 128 + DT_RANK + D_STATE + 8);
            const float dlul = dl * ul;
            const unsigned int bw[8] = {B0.x,B0.y,B0.z,B0.w,B1.x,B1.y,B1.z,B1.w};
            const unsigned int cw_[8] = {C0.x,C0.y,C0.z,C0.w,C1.x,C1.y,C1.z,C1.w};
            float p = 0.f;
            #pragma unroll
            for (int j = 0; j < 16; ++j) {
                const float Bn = (j & 1) ? bfu_hi(bw[j >> 1]) : bfu_lo(bw[j >> 1]);
                const float Cn = (j & 1) ? bfu_hi(cw_[j >> 1]) : bfu_lo(cw_[j >> 1]);
                h[j] = exp2f(dl * A2[j]) * h[j] + dlul * Bn;
                p += h[j] * Cn;
            }
            const float vv = bf2f(uv[tok * (2*D_INNER) + D_INNER + d]);
            uv[tok * (2*D_INNER) + d] = f2bf((p + ul * Dd) * (vv / (1.f + __expf(-vv))));
        }
    }
}

extern "C" void kernel_launch(void* const* d_in, const int* in_sizes, int n_in,
                              void* d_out, int out_size, void* d_ws, size_t ws_size,
                              hipStream_t stream)
{
    const void* x      = d_in[0];
    const void* ln_g   = d_in[1];
    const void* ln_b   = d_in[2];
    const void* W_in   = d_in[3];
    const void* conv_w = d_in[4];
    const void* conv_b = d_in[5];
    const void* W_xp   = d_in[6];
    const void* W_dt   = d_in[7];
    const void* b_dt   = d_in[8];
    const void* log_A  = d_in[9];
    const void* D_par  = d_in[10];
    const void* W_out  = d_in[11];

    // workspace (~87 MB): flag | xn | uv | us | xdbl | delta | carryH | carrySD |
    //                     WtIn | WtXp | WtDt | WtOut | xdblF (4 split-K slices)
    int* flag  = (int*)d_ws;
    u16* ws    = (u16*)((char*)d_ws + 512);
    u16* xn    = ws;
    u16* uv    = xn + (size_t)TT * D_MODEL;
    u16* us    = uv + (size_t)TT * 2 * D_INNER;
    u16* xdbl  = us + (size_t)TT * D_INNER;
    u16* delta = xdbl + (size_t)TT * 128;
    float* carryH  = (float*)(delta + (size_t)TT * D_INNER);
    float* carrySD = carryH + (size_t)BB * NC * D_INNER * D_STATE;
    u16* WtIn  = (u16*)(carrySD + (size_t)BB * NC * D_INNER);
    u16* WtXp  = WtIn  + (size_t)2 * D_INNER * D_MODEL;
    u16* WtDt  = WtXp  + (size_t)(DT_RANK + 2 * D_STATE) * D_INNER;
    u16* WtOut = WtDt  + (size_t)D_INNER * DT_RANK;
    float* xdblF = (float*)(WtOut + (size_t)D_MODEL * D_INNER);  // 4 x TT x 128 fp32

    // fused: dtype-detect (per-block) + weight transposes (960) + LayerNorm (4096)
    prep_kernel<<<960 + TT, 256, 0, stream>>>(
        W_in, W_xp, W_dt, W_out, WtIn, WtXp, WtDt, WtOut,
        x, ln_g, ln_b, xn, flag);
    // uv = xn @ W_in  (4096x3072, K=768)  [128x128, 768 blocks, depth-3 + swz]
    mfma_gemm128<0><<<dim3(2 * D_INNER / 128, TT / 128), 256, 0, stream>>>(
        xn, WtIn, uv, nullptr, nullptr, flag, D_MODEL, D_MODEL, D_MODEL, 2 * D_INNER);
    // us = silu(causal_conv(uv[:, :1536]))  [8-wide vectorized]
    conv_silu_kernel<<<(TT * D_INNER / 8) / 256, 256, 0, stream>>>(uv, conv_w, conv_b, us, flag);
    // xdbl = us @ W_xproj  (4096x128, K=1536)  [64x64 BK=64, split-K x4 slice-stores]
    mfma_gemm<3, 64><<<dim3(2, TT / 64, SKK), 256, 0, stream>>>(
        us, WtXp, nullptr, nullptr, nullptr, xdblF, flag,
        D_INNER / SKK, D_INNER, D_INNER, 128);
    convert_kernel<<<(TT * 128 + 255) / 256, 256, 0, stream>>>(xdblF, xdbl, TT * 128);
    // delta = softplus(xdbl[:, :96] @ W_dt + b_dt)  (4096x1536, K=96)  [BK=32, depth-3]
    mfma_gemm<1, 32><<<dim3(D_INNER / 64, TT / 64, 1), 256, 0, stream>>>(
        xdbl, WtDt, delta, nullptr, b_dt, nullptr, flag,
        DT_RANK, 128, DT_RANK, D_INNER);
    // chunked selective scan (full-d threads: 768 blocks per pass)
    scan1_kernel<<<dim3(D_INNER / 256, NC, BB), 256, 0, stream>>>(
        delta, us, xdbl, log_A, carrySD, carryH, flag);
    scan2_kernel<<<(BB * D_INNER * D_STATE) / 256, 256, 0, stream>>>(
        carrySD, carryH, log_A, flag);
    scan3_kernel<<<dim3(D_INNER / 256, NC, BB), 256, 0, stream>>>(
        delta, us, xdbl, uv, log_A, D_par, carryH, flag);
    // out = y @ W_out + x  (4096x768, K=1536)  [64x64 BK=64, 768 blocks, depth-3 + swz]
    mfma_gemm<2, 64><<<dim3(D_MODEL / 64, TT / 64, 1), 256, 0, stream>>>(
        uv, WtOut, nullptr, d_out, x, nullptr, flag,
        D_INNER, 2 * D_INNER, D_INNER, D_MODEL);
}